// Round 1
// baseline (842.856 us; speedup 1.0000x reference)
//
#include <hip/hip_runtime.h>
#include <hip/hip_bf16.h>

#define DIN   5120
#define LSEQ  2048
#define BATCH 2
#define MROWS 4096      // BATCH*LSEQ
#define EOUT  192       // DT_RANK + 2N
#define RDT   160       // DT_RANK
#define NST   16

// ---------------- helpers for templated delta storage ----------------
__device__ __forceinline__ void stdelta(float* p, size_t i, float v) { p[i] = v; }
__device__ __forceinline__ void stdelta(__hip_bfloat16* p, size_t i, float v) { p[i] = __float2bfloat16(v); }
__device__ __forceinline__ float lddelta(const float* p, size_t i) { return p[i]; }
__device__ __forceinline__ float lddelta(const __hip_bfloat16* p, size_t i) { return __bfloat162float(p[i]); }

__device__ __forceinline__ float softplus_f(float v) {
    // log1p(exp(v)) = max(v,0) + log1p(exp(-|v|))
    return fmaxf(v, 0.f) + log1pf(expf(-fabsf(v)));
}

// ---------------- K1: x_dbl partials = x @ x_proj_w^T (split-K) ----------------
#define K1_MT 64
#define K1_KC 64
#define K1_KSPLIT 8
__global__ __launch_bounds__(256, 2) void k1_gemm(const float* __restrict__ x,
                                                  const float* __restrict__ w,
                                                  float* __restrict__ part) {
    __shared__ float xs[K1_KC][K1_MT + 4];   // [kk][m]
    __shared__ float ws[K1_KC][EOUT + 4];    // [kk][e]
    const int tid = threadIdx.x;
    const int m_base = blockIdx.x * K1_MT;
    const int k_base = blockIdx.y * (DIN / K1_KSPLIT);
    const int mg = tid & 15;      // 4 rows each
    const int eg = tid >> 4;      // 12 cols each
    const int m0 = mg * 4, e0 = eg * 12;

    float acc[4][12];
    #pragma unroll
    for (int i = 0; i < 4; i++)
        #pragma unroll
        for (int j = 0; j < 12; j++) acc[i][j] = 0.f;

    for (int kc = 0; kc < (DIN / K1_KSPLIT); kc += K1_KC) {
        const int k0 = k_base + kc;
        {   // stage x tile: 64m x 64k (transposed into [k][m])
            int f4i = tid;
            #pragma unroll
            for (int i = 0; i < 4; i++) {
                int m = f4i >> 4, kq = f4i & 15;
                float4 v = *reinterpret_cast<const float4*>(&x[(size_t)(m_base + m) * DIN + k0 + kq * 4]);
                xs[kq * 4 + 0][m] = v.x; xs[kq * 4 + 1][m] = v.y;
                xs[kq * 4 + 2][m] = v.z; xs[kq * 4 + 3][m] = v.w;
                f4i += 256;
            }
        }
        {   // stage w tile: 192e x 64k (transposed into [k][e])
            int f4i = tid;
            #pragma unroll
            for (int i = 0; i < 12; i++) {
                int e = f4i >> 4, kq = f4i & 15;
                float4 v = *reinterpret_cast<const float4*>(&w[(size_t)e * DIN + k0 + kq * 4]);
                ws[kq * 4 + 0][e] = v.x; ws[kq * 4 + 1][e] = v.y;
                ws[kq * 4 + 2][e] = v.z; ws[kq * 4 + 3][e] = v.w;
                f4i += 256;
            }
        }
        __syncthreads();
        #pragma unroll 4
        for (int kk = 0; kk < K1_KC; kk++) {
            float4 xv = *reinterpret_cast<const float4*>(&xs[kk][m0]);
            float4 w0 = *reinterpret_cast<const float4*>(&ws[kk][e0]);
            float4 w1 = *reinterpret_cast<const float4*>(&ws[kk][e0 + 4]);
            float4 w2 = *reinterpret_cast<const float4*>(&ws[kk][e0 + 8]);
            float xr[4] = {xv.x, xv.y, xv.z, xv.w};
            float wr[12] = {w0.x, w0.y, w0.z, w0.w, w1.x, w1.y, w1.z, w1.w,
                            w2.x, w2.y, w2.z, w2.w};
            #pragma unroll
            for (int i = 0; i < 4; i++)
                #pragma unroll
                for (int j = 0; j < 12; j++) acc[i][j] = fmaf(xr[i], wr[j], acc[i][j]);
        }
        __syncthreads();
    }
    float* p = part + (size_t)blockIdx.y * MROWS * EOUT;
    #pragma unroll
    for (int i = 0; i < 4; i++) {
        size_t row = (size_t)(m_base + m0 + i) * EOUT + e0;
        *reinterpret_cast<float4*>(&p[row + 0]) = make_float4(acc[i][0], acc[i][1], acc[i][2], acc[i][3]);
        *reinterpret_cast<float4*>(&p[row + 4]) = make_float4(acc[i][4], acc[i][5], acc[i][6], acc[i][7]);
        *reinterpret_cast<float4*>(&p[row + 8]) = make_float4(acc[i][8], acc[i][9], acc[i][10], acc[i][11]);
    }
}

__global__ void k1_reduce(const float* __restrict__ part, float* __restrict__ xdbl) {
    int i = blockIdx.x * 256 + threadIdx.x;   // float4 index; total MROWS*EOUT/4
    const float4* p = reinterpret_cast<const float4*>(part);
    float4 s = p[i];
    #pragma unroll
    for (int k = 1; k < K1_KSPLIT; k++) {
        float4 v = p[(size_t)k * (MROWS * EOUT / 4) + i];
        s.x += v.x; s.y += v.y; s.z += v.z; s.w += v.w;
    }
    reinterpret_cast<float4*>(xdbl)[i] = s;
}

// ---------------- K2: delta = softplus(dt_raw @ dt_proj_w^T + b) ----------------
#define K2_MT 32
#define K2_DTL 128
#define K2_KC 32
template <typename DT>
__global__ __launch_bounds__(256) void k2_delta(const float* __restrict__ xdbl,
                                                const float* __restrict__ w2,
                                                const float* __restrict__ bias,
                                                DT* __restrict__ delta) {
    __shared__ float as[K2_KC][K2_MT + 2];     // [kk][m]
    __shared__ float bs[K2_KC][K2_DTL + 4];    // [kk][d]
    const int tid = threadIdx.x;
    const int m_base = blockIdx.x * K2_MT;
    const int d_base = blockIdx.y * K2_DTL;
    const int dg = tid & 15, mg = tid >> 4;
    const int m0 = mg * 2, d0 = dg * 8;
    float acc[2][8];
    #pragma unroll
    for (int i = 0; i < 2; i++)
        #pragma unroll
        for (int j = 0; j < 8; j++) acc[i][j] = 0.f;

    for (int kc = 0; kc < RDT; kc += K2_KC) {
        {   // stage A: 32m x 32k from xdbl (row stride EOUT)
            int m = tid >> 3, kq = tid & 7;
            float4 v = *reinterpret_cast<const float4*>(&xdbl[(size_t)(m_base + m) * EOUT + kc + kq * 4]);
            as[kq * 4 + 0][m] = v.x; as[kq * 4 + 1][m] = v.y;
            as[kq * 4 + 2][m] = v.z; as[kq * 4 + 3][m] = v.w;
        }
        {   // stage B: 128d x 32k from dt_proj_w (row stride RDT)
            int f4i = tid;
            #pragma unroll
            for (int i = 0; i < 4; i++) {
                int d = f4i >> 3, kq = f4i & 7;
                float4 v = *reinterpret_cast<const float4*>(&w2[(size_t)(d_base + d) * RDT + kc + kq * 4]);
                bs[kq * 4 + 0][d] = v.x; bs[kq * 4 + 1][d] = v.y;
                bs[kq * 4 + 2][d] = v.z; bs[kq * 4 + 3][d] = v.w;
                f4i += 256;
            }
        }
        __syncthreads();
        #pragma unroll 8
        for (int kk = 0; kk < K2_KC; kk++) {
            float2 av = *reinterpret_cast<const float2*>(&as[kk][m0]);
            float4 b0 = *reinterpret_cast<const float4*>(&bs[kk][d0]);
            float4 b1 = *reinterpret_cast<const float4*>(&bs[kk][d0 + 4]);
            float ar[2] = {av.x, av.y};
            float br[8] = {b0.x, b0.y, b0.z, b0.w, b1.x, b1.y, b1.z, b1.w};
            #pragma unroll
            for (int i = 0; i < 2; i++)
                #pragma unroll
                for (int j = 0; j < 8; j++) acc[i][j] = fmaf(ar[i], br[j], acc[i][j]);
        }
        __syncthreads();
    }
    #pragma unroll
    for (int i = 0; i < 2; i++) {
        size_t row = (size_t)(m_base + m0 + i) * DIN + d_base + d0;
        #pragma unroll
        for (int j = 0; j < 8; j++) {
            float v = acc[i][j] + bias[d_base + d0 + j];
            stdelta(delta, row + j, softplus_f(v));
        }
    }
}

// ---------------- K3: sequential selective scan ----------------
template <typename DT>
__global__ __launch_bounds__(256) void k3_scan(const float* __restrict__ x,
                                               const DT* __restrict__ delta,
                                               const float* __restrict__ xdbl,
                                               const float* __restrict__ A_log,
                                               const float* __restrict__ Dw,
                                               float* __restrict__ out) {
    __shared__ float xs[64][16];
    __shared__ float dls[64][16];
    __shared__ float Bs[64][16];
    __shared__ float Cs[64][16];
    __shared__ float ys[64][16];
    const int tid = threadIdx.x;
    const int dblk = blockIdx.x;          // 0..319
    const int b = blockIdx.y;             // 0..1
    const int n = tid & 15, dl = tid >> 4;
    const int d = dblk * 16 + dl;
    const float A2 = -expf(A_log[d * NST + n]) * 1.44269504089f;  // A*log2(e)
    const float Dv = Dw[dblk * 16 + (tid & 15)];                  // for writer role (c == tid&15)
    float h = 0.f;
    const size_t xbase = (size_t)b * LSEQ * DIN + dblk * 16;
    const size_t ebase = (size_t)b * LSEQ * EOUT;

    for (int t0 = 0; t0 < LSEQ; t0 += 64) {
        #pragma unroll
        for (int i = 0; i < 4; i++) {     // stage 64 timesteps
            int idx = tid + 256 * i;
            int tt = idx >> 4, c = idx & 15;
            size_t g = xbase + (size_t)(t0 + tt) * DIN + c;
            xs[tt][c] = x[g];
            dls[tt][c] = lddelta(delta, g);
            size_t ge = ebase + (size_t)(t0 + tt) * EOUT;
            Bs[tt][c] = xdbl[ge + RDT + c];
            Cs[tt][c] = xdbl[ge + RDT + NST + c];
        }
        __syncthreads();
        for (int tt = 0; tt < 64; tt++) {
            float dv = dls[tt][dl];
            float dA = exp2f(dv * A2);
            float u = dv * xs[tt][dl] * Bs[tt][n];
            h = fmaf(dA, h, u);
            float p = h * Cs[tt][n];
            p += __shfl_xor(p, 1);
            p += __shfl_xor(p, 2);
            p += __shfl_xor(p, 4);
            p += __shfl_xor(p, 8);
            if (n == 0) ys[tt][dl] = p;
        }
        __syncthreads();
        #pragma unroll
        for (int i = 0; i < 4; i++) {     // write out: y + x*D
            int idx = tid + 256 * i;
            int tt = idx >> 4, c = idx & 15;
            size_t g = xbase + (size_t)(t0 + tt) * DIN + c;
            out[g] = ys[tt][c] + xs[tt][c] * Dv;
        }
        __syncthreads();
    }
}

extern "C" void kernel_launch(void* const* d_in, const int* in_sizes, int n_in,
                              void* d_out, int out_size, void* d_ws, size_t ws_size,
                              hipStream_t stream) {
    const float* x     = (const float*)d_in[0];
    const float* A_log = (const float*)d_in[1];
    const float* Dw    = (const float*)d_in[2];
    const float* xpw   = (const float*)d_in[3];
    const float* dtw   = (const float*)d_in[4];
    const float* dtb   = (const float*)d_in[5];
    float* out = (float*)d_out;

    char* ws = (char*)d_ws;
    size_t off = 0;
    float* part = (float*)(ws + off); off += (size_t)K1_KSPLIT * MROWS * EOUT * 4;
    float* xdbl = (float*)(ws + off); off += (size_t)MROWS * EOUT * 4;
    const size_t delta_off = off;
    const bool f32ok = ws_size >= delta_off + (size_t)MROWS * DIN * 4;

    k1_gemm<<<dim3(MROWS / K1_MT, K1_KSPLIT), 256, 0, stream>>>(x, xpw, part);
    k1_reduce<<<dim3(MROWS * EOUT / 4 / 256), 256, 0, stream>>>(part, xdbl);

    if (f32ok) {
        float* delta = (float*)(ws + delta_off);
        k2_delta<float><<<dim3(MROWS / K2_MT, DIN / K2_DTL), 256, 0, stream>>>(xdbl, dtw, dtb, delta);
        k3_scan<float><<<dim3(DIN / 16, BATCH), 256, 0, stream>>>(x, delta, xdbl, A_log, Dw, out);
    } else {
        __hip_bfloat16* delta = (__hip_bfloat16*)(ws + delta_off);
        k2_delta<__hip_bfloat16><<<dim3(MROWS / K2_MT, DIN / K2_DTL), 256, 0, stream>>>(xdbl, dtw, dtb, delta);
        k3_scan<__hip_bfloat16><<<dim3(DIN / 16, BATCH), 256, 0, stream>>>(x, delta, xdbl, A_log, Dw, out);
    }
}

// Round 2
// 429.827 us; speedup vs baseline: 1.9609x; 1.9609x over previous
//
#include <hip/hip_runtime.h>
#include <hip/hip_bf16.h>

#define DIN   5120
#define LSEQ  2048
#define BATCH 2
#define MROWS 4096      // BATCH*LSEQ
#define EOUT  192       // DT_RANK + 2N
#define RDT   160       // DT_RANK
#define NST   16
#define NC    32        // scan chunks
#define LC    64        // timesteps per chunk (NC*LC == LSEQ)
#define LOG2E 1.44269504088896f

// ---------------- helpers for templated delta storage ----------------
__device__ __forceinline__ void stdelta(float* p, size_t i, float v) { p[i] = v; }
__device__ __forceinline__ void stdelta(__hip_bfloat16* p, size_t i, float v) { p[i] = __float2bfloat16(v); }
__device__ __forceinline__ float lddelta(const float* p, size_t i) { return p[i]; }
__device__ __forceinline__ float lddelta(const __hip_bfloat16* p, size_t i) { return __bfloat162float(p[i]); }

__device__ __forceinline__ float softplus_f(float v) {
    return fmaxf(v, 0.f) + log1pf(expf(-fabsf(v)));
}

// ---------------- K1: x_dbl partials = x @ x_proj_w^T (split-K) ----------------
#define K1_MT 64
#define K1_KC 64
#define K1_KSPLIT 8
__global__ __launch_bounds__(256, 2) void k1_gemm(const float* __restrict__ x,
                                                  const float* __restrict__ w,
                                                  float* __restrict__ part) {
    __shared__ float xs[K1_KC][K1_MT + 4];   // [kk][m]
    __shared__ float ws[K1_KC][EOUT + 4];    // [kk][e]
    const int tid = threadIdx.x;
    const int m_base = blockIdx.x * K1_MT;
    const int k_base = blockIdx.y * (DIN / K1_KSPLIT);
    const int mg = tid & 15;      // 4 rows each
    const int eg = tid >> 4;      // 12 cols each
    const int m0 = mg * 4, e0 = eg * 12;

    float acc[4][12];
    #pragma unroll
    for (int i = 0; i < 4; i++)
        #pragma unroll
        for (int j = 0; j < 12; j++) acc[i][j] = 0.f;

    for (int kc = 0; kc < (DIN / K1_KSPLIT); kc += K1_KC) {
        const int k0 = k_base + kc;
        {   // stage x tile: 64m x 64k (transposed into [k][m])
            int f4i = tid;
            #pragma unroll
            for (int i = 0; i < 4; i++) {
                int m = f4i >> 4, kq = f4i & 15;
                float4 v = *reinterpret_cast<const float4*>(&x[(size_t)(m_base + m) * DIN + k0 + kq * 4]);
                xs[kq * 4 + 0][m] = v.x; xs[kq * 4 + 1][m] = v.y;
                xs[kq * 4 + 2][m] = v.z; xs[kq * 4 + 3][m] = v.w;
                f4i += 256;
            }
        }
        {   // stage w tile: 192e x 64k (transposed into [k][e])
            int f4i = tid;
            #pragma unroll
            for (int i = 0; i < 12; i++) {
                int e = f4i >> 4, kq = f4i & 15;
                float4 v = *reinterpret_cast<const float4*>(&w[(size_t)e * DIN + k0 + kq * 4]);
                ws[kq * 4 + 0][e] = v.x; ws[kq * 4 + 1][e] = v.y;
                ws[kq * 4 + 2][e] = v.z; ws[kq * 4 + 3][e] = v.w;
                f4i += 256;
            }
        }
        __syncthreads();
        #pragma unroll 4
        for (int kk = 0; kk < K1_KC; kk++) {
            float4 xv = *reinterpret_cast<const float4*>(&xs[kk][m0]);
            float4 w0 = *reinterpret_cast<const float4*>(&ws[kk][e0]);
            float4 w1 = *reinterpret_cast<const float4*>(&ws[kk][e0 + 4]);
            float4 w2 = *reinterpret_cast<const float4*>(&ws[kk][e0 + 8]);
            float xr[4] = {xv.x, xv.y, xv.z, xv.w};
            float wr[12] = {w0.x, w0.y, w0.z, w0.w, w1.x, w1.y, w1.z, w1.w,
                            w2.x, w2.y, w2.z, w2.w};
            #pragma unroll
            for (int i = 0; i < 4; i++)
                #pragma unroll
                for (int j = 0; j < 12; j++) acc[i][j] = fmaf(xr[i], wr[j], acc[i][j]);
        }
        __syncthreads();
    }
    float* p = part + (size_t)blockIdx.y * MROWS * EOUT;
    #pragma unroll
    for (int i = 0; i < 4; i++) {
        size_t row = (size_t)(m_base + m0 + i) * EOUT + e0;
        *reinterpret_cast<float4*>(&p[row + 0]) = make_float4(acc[i][0], acc[i][1], acc[i][2], acc[i][3]);
        *reinterpret_cast<float4*>(&p[row + 4]) = make_float4(acc[i][4], acc[i][5], acc[i][6], acc[i][7]);
        *reinterpret_cast<float4*>(&p[row + 8]) = make_float4(acc[i][8], acc[i][9], acc[i][10], acc[i][11]);
    }
}

__global__ void k1_reduce(const float* __restrict__ part, float* __restrict__ xdbl) {
    int i = blockIdx.x * 256 + threadIdx.x;   // float4 index; total MROWS*EOUT/4
    const float4* p = reinterpret_cast<const float4*>(part);
    float4 s = p[i];
    #pragma unroll
    for (int k = 1; k < K1_KSPLIT; k++) {
        float4 v = p[(size_t)k * (MROWS * EOUT / 4) + i];
        s.x += v.x; s.y += v.y; s.z += v.z; s.w += v.w;
    }
    reinterpret_cast<float4*>(xdbl)[i] = s;
}

// ---------------- K2: delta = softplus(dt_raw @ dt_proj_w^T + b) ----------------
#define K2_MT 32
#define K2_DTL 128
#define K2_KC 32
template <typename DT>
__global__ __launch_bounds__(256) void k2_delta(const float* __restrict__ xdbl,
                                                const float* __restrict__ w2,
                                                const float* __restrict__ bias,
                                                DT* __restrict__ delta) {
    __shared__ float as[K2_KC][K2_MT + 2];     // [kk][m]
    __shared__ float bs[K2_KC][K2_DTL + 4];    // [kk][d]
    const int tid = threadIdx.x;
    const int m_base = blockIdx.x * K2_MT;
    const int d_base = blockIdx.y * K2_DTL;
    const int dg = tid & 15, mg = tid >> 4;
    const int m0 = mg * 2, d0 = dg * 8;
    float acc[2][8];
    #pragma unroll
    for (int i = 0; i < 2; i++)
        #pragma unroll
        for (int j = 0; j < 8; j++) acc[i][j] = 0.f;

    for (int kc = 0; kc < RDT; kc += K2_KC) {
        {
            int m = tid >> 3, kq = tid & 7;
            float4 v = *reinterpret_cast<const float4*>(&xdbl[(size_t)(m_base + m) * EOUT + kc + kq * 4]);
            as[kq * 4 + 0][m] = v.x; as[kq * 4 + 1][m] = v.y;
            as[kq * 4 + 2][m] = v.z; as[kq * 4 + 3][m] = v.w;
        }
        {
            int f4i = tid;
            #pragma unroll
            for (int i = 0; i < 4; i++) {
                int d = f4i >> 3, kq = f4i & 7;
                float4 v = *reinterpret_cast<const float4*>(&w2[(size_t)(d_base + d) * RDT + kc + kq * 4]);
                bs[kq * 4 + 0][d] = v.x; bs[kq * 4 + 1][d] = v.y;
                bs[kq * 4 + 2][d] = v.z; bs[kq * 4 + 3][d] = v.w;
                f4i += 256;
            }
        }
        __syncthreads();
        #pragma unroll 8
        for (int kk = 0; kk < K2_KC; kk++) {
            float2 av = *reinterpret_cast<const float2*>(&as[kk][m0]);
            float4 b0 = *reinterpret_cast<const float4*>(&bs[kk][d0]);
            float4 b1 = *reinterpret_cast<const float4*>(&bs[kk][d0 + 4]);
            float ar[2] = {av.x, av.y};
            float br[8] = {b0.x, b0.y, b0.z, b0.w, b1.x, b1.y, b1.z, b1.w};
            #pragma unroll
            for (int i = 0; i < 2; i++)
                #pragma unroll
                for (int j = 0; j < 8; j++) acc[i][j] = fmaf(ar[i], br[j], acc[i][j]);
        }
        __syncthreads();
    }
    #pragma unroll
    for (int i = 0; i < 2; i++) {
        size_t row = (size_t)(m_base + m0 + i) * DIN + d_base + d0;
        #pragma unroll
        for (int j = 0; j < 8; j++) {
            float v = acc[i][j] + bias[d_base + d0 + j];
            stdelta(delta, row + j, softplus_f(v));
        }
    }
}

// ---------------- K3a: per-chunk local scan (h from 0), emit hend0 + S=sum(delta) ----------------
template <typename DT>
__global__ __launch_bounds__(256) void k3a_local(const float* __restrict__ x,
                                                 const DT* __restrict__ delta,
                                                 const float* __restrict__ xdbl,
                                                 const float* __restrict__ A_log,
                                                 float* __restrict__ Sbuf,
                                                 float* __restrict__ hend0) {
    const int tid = threadIdx.x;
    const int d = blockIdx.x * 256 + tid;
    const int c = blockIdx.y, b = blockIdx.z;

    float4 aq[4];
    #pragma unroll
    for (int q = 0; q < 4; q++) aq[q] = *reinterpret_cast<const float4*>(&A_log[d * NST + q * 4]);
    const float* av = reinterpret_cast<const float*>(aq);
    float A2[NST];
    #pragma unroll
    for (int n = 0; n < NST; n++) A2[n] = -expf(av[n]) * LOG2E;

    float h[NST];
    #pragma unroll
    for (int n = 0; n < NST; n++) h[n] = 0.f;
    float S = 0.f;

    const size_t gbase = (size_t)b * LSEQ * DIN + (size_t)c * LC * DIN + d;
    const float* Bbase = xdbl + ((size_t)b * LSEQ + (size_t)c * LC) * EOUT + RDT;

    float dv = lddelta(delta, gbase);
    float xv = x[gbase];
    float4 bq[4];
    {
        const float4* Bp = reinterpret_cast<const float4*>(Bbase);
        bq[0] = Bp[0]; bq[1] = Bp[1]; bq[2] = Bp[2]; bq[3] = Bp[3];
    }
    for (int tt = 0; tt < LC; tt++) {
        const int ttn = (tt + 1 < LC) ? tt + 1 : tt;
        float dv_n = lddelta(delta, gbase + (size_t)ttn * DIN);
        float xv_n = x[gbase + (size_t)ttn * DIN];
        float4 bqn[4];
        {
            const float4* Bp = reinterpret_cast<const float4*>(Bbase + (size_t)ttn * EOUT);
            bqn[0] = Bp[0]; bqn[1] = Bp[1]; bqn[2] = Bp[2]; bqn[3] = Bp[3];
        }
        const float* Bv = reinterpret_cast<const float*>(bq);
        S += dv;
        const float dvx = dv * xv;
        #pragma unroll
        for (int n = 0; n < NST; n++)
            h[n] = fmaf(__builtin_amdgcn_exp2f(dv * A2[n]), h[n], dvx * Bv[n]);
        dv = dv_n; xv = xv_n;
        bq[0] = bqn[0]; bq[1] = bqn[1]; bq[2] = bqn[2]; bq[3] = bqn[3];
    }
    Sbuf[((size_t)b * NC + c) * DIN + d] = S;
    float* hp = hend0 + (((size_t)b * NC + c) * DIN + d) * NST;
    #pragma unroll
    for (int q = 0; q < 4; q++)
        reinterpret_cast<float4*>(hp)[q] = make_float4(h[q*4], h[q*4+1], h[q*4+2], h[q*4+3]);
}

// ---------------- K3b: sequential chunk combine -> hinit per chunk ----------------
__global__ __launch_bounds__(256) void k3b_combine(const float* __restrict__ Sbuf,
                                                   const float* __restrict__ hend0,
                                                   const float* __restrict__ A_log,
                                                   float* __restrict__ hinit) {
    const int i = blockIdx.x * 256 + threadIdx.x;   // < BATCH*DIN*NST
    const int b = i / (DIN * NST);
    const int r = i % (DIN * NST);
    const int d = r >> 4;
    const float A2 = -expf(A_log[r]) * LOG2E;
    float hi = 0.f;
    for (int c = 0; c < NC; c++) {
        const size_t idx = ((size_t)b * NC + c) * DIN * NST + r;
        hinit[idx] = hi;
        hi = fmaf(__builtin_amdgcn_exp2f(Sbuf[((size_t)b * NC + c) * DIN + d] * A2), hi, hend0[idx]);
    }
}

// ---------------- K3c: per-chunk scan from hinit, emit y ----------------
template <typename DT>
__global__ __launch_bounds__(256) void k3c_scan(const float* __restrict__ x,
                                                const DT* __restrict__ delta,
                                                const float* __restrict__ xdbl,
                                                const float* __restrict__ A_log,
                                                const float* __restrict__ Dw,
                                                const float* __restrict__ hinit,
                                                float* __restrict__ out) {
    const int tid = threadIdx.x;
    const int d = blockIdx.x * 256 + tid;
    const int c = blockIdx.y, b = blockIdx.z;

    float4 aq[4];
    #pragma unroll
    for (int q = 0; q < 4; q++) aq[q] = *reinterpret_cast<const float4*>(&A_log[d * NST + q * 4]);
    const float* av = reinterpret_cast<const float*>(aq);
    float A2[NST];
    #pragma unroll
    for (int n = 0; n < NST; n++) A2[n] = -expf(av[n]) * LOG2E;

    float h[NST];
    {
        const float* hp = hinit + (((size_t)b * NC + c) * DIN + d) * NST;
        float4 hq[4];
        #pragma unroll
        for (int q = 0; q < 4; q++) hq[q] = reinterpret_cast<const float4*>(hp)[q];
        const float* hv = reinterpret_cast<const float*>(hq);
        #pragma unroll
        for (int n = 0; n < NST; n++) h[n] = hv[n];
    }
    const float Dv = Dw[d];

    const size_t gbase = (size_t)b * LSEQ * DIN + (size_t)c * LC * DIN + d;
    const float* Bbase = xdbl + ((size_t)b * LSEQ + (size_t)c * LC) * EOUT + RDT;

    float dv = lddelta(delta, gbase);
    float xv = x[gbase];
    float4 bq[4], cq[4];
    {
        const float4* Bp = reinterpret_cast<const float4*>(Bbase);
        bq[0] = Bp[0]; bq[1] = Bp[1]; bq[2] = Bp[2]; bq[3] = Bp[3];
        cq[0] = Bp[4]; cq[1] = Bp[5]; cq[2] = Bp[6]; cq[3] = Bp[7];
    }
    for (int tt = 0; tt < LC; tt++) {
        const int ttn = (tt + 1 < LC) ? tt + 1 : tt;
        float dv_n = lddelta(delta, gbase + (size_t)ttn * DIN);
        float xv_n = x[gbase + (size_t)ttn * DIN];
        float4 bqn[4], cqn[4];
        {
            const float4* Bp = reinterpret_cast<const float4*>(Bbase + (size_t)ttn * EOUT);
            bqn[0] = Bp[0]; bqn[1] = Bp[1]; bqn[2] = Bp[2]; bqn[3] = Bp[3];
            cqn[0] = Bp[4]; cqn[1] = Bp[5]; cqn[2] = Bp[6]; cqn[3] = Bp[7];
        }
        const float* Bv = reinterpret_cast<const float*>(bq);
        const float* Cv = reinterpret_cast<const float*>(cq);
        const float dvx = dv * xv;
        float y0 = 0.f, y1 = 0.f, y2 = 0.f, y3 = 0.f;
        #pragma unroll
        for (int n = 0; n < NST; n += 4) {
            h[n+0] = fmaf(__builtin_amdgcn_exp2f(dv * A2[n+0]), h[n+0], dvx * Bv[n+0]);
            y0 = fmaf(h[n+0], Cv[n+0], y0);
            h[n+1] = fmaf(__builtin_amdgcn_exp2f(dv * A2[n+1]), h[n+1], dvx * Bv[n+1]);
            y1 = fmaf(h[n+1], Cv[n+1], y1);
            h[n+2] = fmaf(__builtin_amdgcn_exp2f(dv * A2[n+2]), h[n+2], dvx * Bv[n+2]);
            y2 = fmaf(h[n+2], Cv[n+2], y2);
            h[n+3] = fmaf(__builtin_amdgcn_exp2f(dv * A2[n+3]), h[n+3], dvx * Bv[n+3]);
            y3 = fmaf(h[n+3], Cv[n+3], y3);
        }
        out[gbase + (size_t)tt * DIN] = ((y0 + y1) + (y2 + y3)) + xv * Dv;
        dv = dv_n; xv = xv_n;
        bq[0] = bqn[0]; bq[1] = bqn[1]; bq[2] = bqn[2]; bq[3] = bqn[3];
        cq[0] = cqn[0]; cq[1] = cqn[1]; cq[2] = cqn[2]; cq[3] = cqn[3];
    }
}

extern "C" void kernel_launch(void* const* d_in, const int* in_sizes, int n_in,
                              void* d_out, int out_size, void* d_ws, size_t ws_size,
                              hipStream_t stream) {
    const float* x     = (const float*)d_in[0];
    const float* A_log = (const float*)d_in[1];
    const float* Dw    = (const float*)d_in[2];
    const float* xpw   = (const float*)d_in[3];
    const float* dtw   = (const float*)d_in[4];
    const float* dtb   = (const float*)d_in[5];
    float* out = (float*)d_out;

    char* ws = (char*)d_ws;
    size_t off = 0;
    float* xdbl  = (float*)(ws + off); off += (size_t)MROWS * EOUT * 4;           // 3.15 MB
    float* hend0 = (float*)(ws + off); off += (size_t)BATCH * NC * DIN * NST * 4; // 20.97 MB
    float* hinit = (float*)(ws + off); off += (size_t)BATCH * NC * DIN * NST * 4; // 20.97 MB
    float* Sbuf  = (float*)(ws + off); off += (size_t)BATCH * NC * DIN * 4;       // 1.31 MB
    // K1 split-K partials alias hend0+hinit (dead before phase 1 writes them):
    float* part = hend0;  // needs 25.2 MB <= 41.9 MB available
    const size_t delta_off = off;
    const bool f32ok = ws_size >= delta_off + (size_t)MROWS * DIN * 4;

    k1_gemm<<<dim3(MROWS / K1_MT, K1_KSPLIT), 256, 0, stream>>>(x, xpw, part);
    k1_reduce<<<dim3(MROWS * EOUT / 4 / 256), 256, 0, stream>>>(part, xdbl);

    if (f32ok) {
        float* delta = (float*)(ws + delta_off);
        k2_delta<float><<<dim3(MROWS / K2_MT, DIN / K2_DTL), 256, 0, stream>>>(xdbl, dtw, dtb, delta);
        k3a_local<float><<<dim3(DIN / 256, NC, BATCH), 256, 0, stream>>>(x, delta, xdbl, A_log, Sbuf, hend0);
        k3b_combine<<<dim3(BATCH * DIN * NST / 256), 256, 0, stream>>>(Sbuf, hend0, A_log, hinit);
        k3c_scan<float><<<dim3(DIN / 256, NC, BATCH), 256, 0, stream>>>(x, delta, xdbl, A_log, Dw, hinit, out);
    } else {
        __hip_bfloat16* delta = (__hip_bfloat16*)(ws + delta_off);
        k2_delta<__hip_bfloat16><<<dim3(MROWS / K2_MT, DIN / K2_DTL), 256, 0, stream>>>(xdbl, dtw, dtb, delta);
        k3a_local<__hip_bfloat16><<<dim3(DIN / 256, NC, BATCH), 256, 0, stream>>>(x, delta, xdbl, A_log, Sbuf, hend0);
        k3b_combine<<<dim3(BATCH * DIN * NST / 256), 256, 0, stream>>>(Sbuf, hend0, A_log, hinit);
        k3c_scan<__hip_bfloat16><<<dim3(DIN / 256, NC, BATCH), 256, 0, stream>>>(x, delta, xdbl, A_log, Dw, hinit, out);
    }
}

// Round 3
// 372.665 us; speedup vs baseline: 2.2617x; 1.1534x over previous
//
#include <hip/hip_runtime.h>
#include <hip/hip_bf16.h>

#define DIN   5120
#define LSEQ  2048
#define BATCH 2
#define MROWS 4096      // BATCH*LSEQ
#define EOUT  192       // DT_RANK + 2N
#define RDT   160       // DT_RANK
#define NST   16
#define NC    32        // scan chunks
#define LC    64        // timesteps per chunk (NC*LC == LSEQ)
#define LOG2E 1.44269504088896f

typedef __attribute__((ext_vector_type(8))) short bf16x8;
typedef __attribute__((ext_vector_type(4))) float f32x4;

// ---------------- helpers for templated delta storage ----------------
__device__ __forceinline__ void stdelta(float* p, size_t i, float v) { p[i] = v; }
__device__ __forceinline__ void stdelta(__hip_bfloat16* p, size_t i, float v) { p[i] = __float2bfloat16(v); }
__device__ __forceinline__ float lddelta(const float* p, size_t i) { return p[i]; }
__device__ __forceinline__ float lddelta(const __hip_bfloat16* p, size_t i) { return __bfloat162float(p[i]); }

__device__ __forceinline__ float softplus_f(float v) {
    return fmaxf(v, 0.f) + log1pf(expf(-fabsf(v)));
}

// ---------------- K1: x_dbl partials = x @ x_proj_w^T (split-K) ----------------
#define K1_MT 64
#define K1_KC 64
#define K1_KSPLIT 8
__global__ __launch_bounds__(256, 2) void k1_gemm(const float* __restrict__ x,
                                                  const float* __restrict__ w,
                                                  float* __restrict__ part) {
    __shared__ float xs[K1_KC][K1_MT + 4];   // [kk][m]
    __shared__ float ws[K1_KC][EOUT + 4];    // [kk][e]
    const int tid = threadIdx.x;
    const int m_base = blockIdx.x * K1_MT;
    const int k_base = blockIdx.y * (DIN / K1_KSPLIT);
    const int mg = tid & 15;
    const int eg = tid >> 4;
    const int m0 = mg * 4, e0 = eg * 12;

    float acc[4][12];
    #pragma unroll
    for (int i = 0; i < 4; i++)
        #pragma unroll
        for (int j = 0; j < 12; j++) acc[i][j] = 0.f;

    for (int kc = 0; kc < (DIN / K1_KSPLIT); kc += K1_KC) {
        const int k0 = k_base + kc;
        {
            int f4i = tid;
            #pragma unroll
            for (int i = 0; i < 4; i++) {
                int m = f4i >> 4, kq = f4i & 15;
                float4 v = *reinterpret_cast<const float4*>(&x[(size_t)(m_base + m) * DIN + k0 + kq * 4]);
                xs[kq * 4 + 0][m] = v.x; xs[kq * 4 + 1][m] = v.y;
                xs[kq * 4 + 2][m] = v.z; xs[kq * 4 + 3][m] = v.w;
                f4i += 256;
            }
        }
        {
            int f4i = tid;
            #pragma unroll
            for (int i = 0; i < 12; i++) {
                int e = f4i >> 4, kq = f4i & 15;
                float4 v = *reinterpret_cast<const float4*>(&w[(size_t)e * DIN + k0 + kq * 4]);
                ws[kq * 4 + 0][e] = v.x; ws[kq * 4 + 1][e] = v.y;
                ws[kq * 4 + 2][e] = v.z; ws[kq * 4 + 3][e] = v.w;
                f4i += 256;
            }
        }
        __syncthreads();
        #pragma unroll 4
        for (int kk = 0; kk < K1_KC; kk++) {
            float4 xv = *reinterpret_cast<const float4*>(&xs[kk][m0]);
            float4 w0 = *reinterpret_cast<const float4*>(&ws[kk][e0]);
            float4 w1 = *reinterpret_cast<const float4*>(&ws[kk][e0 + 4]);
            float4 w2 = *reinterpret_cast<const float4*>(&ws[kk][e0 + 8]);
            float xr[4] = {xv.x, xv.y, xv.z, xv.w};
            float wr[12] = {w0.x, w0.y, w0.z, w0.w, w1.x, w1.y, w1.z, w1.w,
                            w2.x, w2.y, w2.z, w2.w};
            #pragma unroll
            for (int i = 0; i < 4; i++)
                #pragma unroll
                for (int j = 0; j < 12; j++) acc[i][j] = fmaf(xr[i], wr[j], acc[i][j]);
        }
        __syncthreads();
    }
    float* p = part + (size_t)blockIdx.y * MROWS * EOUT;
    #pragma unroll
    for (int i = 0; i < 4; i++) {
        size_t row = (size_t)(m_base + m0 + i) * EOUT + e0;
        *reinterpret_cast<float4*>(&p[row + 0]) = make_float4(acc[i][0], acc[i][1], acc[i][2], acc[i][3]);
        *reinterpret_cast<float4*>(&p[row + 4]) = make_float4(acc[i][4], acc[i][5], acc[i][6], acc[i][7]);
        *reinterpret_cast<float4*>(&p[row + 8]) = make_float4(acc[i][8], acc[i][9], acc[i][10], acc[i][11]);
    }
}

__global__ void k1_reduce(const float* __restrict__ part, float* __restrict__ xdbl) {
    int i = blockIdx.x * 256 + threadIdx.x;
    const float4* p = reinterpret_cast<const float4*>(part);
    float4 s = p[i];
    #pragma unroll
    for (int k = 1; k < K1_KSPLIT; k++) {
        float4 v = p[(size_t)k * (MROWS * EOUT / 4) + i];
        s.x += v.x; s.y += v.y; s.z += v.z; s.w += v.w;
    }
    reinterpret_cast<float4*>(xdbl)[i] = s;
}

// ---------------- K2 (MFMA): delta = softplus(dtraw @ w2^T + b) ----------------
// M=4096, N=5120, K=160. Tile 64m x 256d, K staged whole. 2-pass A-split
// (x = hi + lo, bf16 trunc) for near-fp32 A precision; B single bf16.
// LDS: a_hi[64][160], a_lo[64][160], b[256][160] bf16, XOR-swizzled
// (byte ^= (row&7)<<4) -> conflict-free-ish ds_read_b128. Total 120 KiB.
#define A_HI_OFF 0
#define A_LO_OFF 20480
#define B_OFF    40960

template <typename DT>
__global__ __launch_bounds__(256) void k2_mfma(const float* __restrict__ xdbl,
                                               const float* __restrict__ w2,
                                               const float* __restrict__ bias,
                                               DT* __restrict__ delta) {
    __shared__ char smem[122880];
    const int tid = threadIdx.x;
    const int m_base = blockIdx.x * 64;
    const int d_base = blockIdx.y * 256;

    // ---- stage A (dtraw 64x160) as bf16 hi/lo, trunc split ----
    #pragma unroll
    for (int it = 0; it < 10; ++it) {
        int pi = tid + it * 256;              // 0..2559 ushort4-packs
        int row = pi / 40, kq = pi % 40;      // k = kq*4
        float4 v = *reinterpret_cast<const float4*>(&xdbl[(size_t)(m_base + row) * EOUT + kq * 4]);
        uint ux = __float_as_uint(v.x), uy = __float_as_uint(v.y);
        uint uz = __float_as_uint(v.z), uw = __float_as_uint(v.w);
        uint hx = ux & 0xFFFF0000u, hy = uy & 0xFFFF0000u;
        uint hz = uz & 0xFFFF0000u, hw = uw & 0xFFFF0000u;
        uint2 hiw = make_uint2((hx >> 16) | hy, (hz >> 16) | hw);
        float lx = v.x - __uint_as_float(hx);
        float ly = v.y - __uint_as_float(hy);
        float lz = v.z - __uint_as_float(hz);
        float lw = v.w - __uint_as_float(hw);
        uint2 low = make_uint2((__float_as_uint(lx) >> 16) | (__float_as_uint(ly) & 0xFFFF0000u),
                               (__float_as_uint(lz) >> 16) | (__float_as_uint(lw) & 0xFFFF0000u));
        int byte = row * 320 + kq * 8;
        byte ^= (row & 7) << 4;
        *reinterpret_cast<uint2*>(smem + A_HI_OFF + byte) = hiw;
        *reinterpret_cast<uint2*>(smem + A_LO_OFF + byte) = low;
    }
    // ---- stage B (w2 256x160) as bf16 trunc ----
    #pragma unroll
    for (int it = 0; it < 40; ++it) {
        int pi = tid + it * 256;              // 0..10239
        int row = pi / 40, kq = pi % 40;
        float4 v = *reinterpret_cast<const float4*>(&w2[(size_t)(d_base + row) * RDT + kq * 4]);
        uint2 hiw = make_uint2((__float_as_uint(v.x) >> 16) | (__float_as_uint(v.y) & 0xFFFF0000u),
                               (__float_as_uint(v.z) >> 16) | (__float_as_uint(v.w) & 0xFFFF0000u));
        int byte = row * 320 + kq * 8;
        byte ^= (row & 7) << 4;
        *reinterpret_cast<uint2*>(smem + B_OFF + byte) = hiw;
    }
    __syncthreads();

    const int lane = tid & 63, w = tid >> 6;
    const int wr = w >> 1, wc = w & 1;        // 2x2 wave grid: wave = 32m x 128d
    const int lr = lane & 15, lg = lane >> 4;

    f32x4 acc[2][8];
    #pragma unroll
    for (int i = 0; i < 2; i++)
        #pragma unroll
        for (int j = 0; j < 8; j++) acc[i][j] = (f32x4)(0.f);

    #pragma unroll
    for (int kk = 0; kk < 5; kk++) {
        const int kb = kk * 64 + lg * 16;     // byte offset of k = kk*32 + lg*8
        bf16x8 ah[2], al[2];
        #pragma unroll
        for (int i = 0; i < 2; i++) {
            int row = wr * 32 + i * 16 + lr;
            int byte = (row * 320 + kb) ^ ((row & 7) << 4);
            ah[i] = *reinterpret_cast<const bf16x8*>(smem + A_HI_OFF + byte);
            al[i] = *reinterpret_cast<const bf16x8*>(smem + A_LO_OFF + byte);
        }
        #pragma unroll
        for (int j = 0; j < 8; j++) {
            int row = wc * 128 + j * 16 + lr;
            int byte = (row * 320 + kb) ^ ((row & 7) << 4);
            bf16x8 bb = *reinterpret_cast<const bf16x8*>(smem + B_OFF + byte);
            #pragma unroll
            for (int i = 0; i < 2; i++) {
                acc[i][j] = __builtin_amdgcn_mfma_f32_16x16x32_bf16(ah[i], bb, acc[i][j], 0, 0, 0);
                acc[i][j] = __builtin_amdgcn_mfma_f32_16x16x32_bf16(al[i], bb, acc[i][j], 0, 0, 0);
            }
        }
    }

    // ---- epilogue: + bias, softplus, store ----
    #pragma unroll
    for (int j = 0; j < 8; j++) {
        const int gd = d_base + wc * 128 + j * 16 + lr;
        const float bv = bias[gd];
        #pragma unroll
        for (int i = 0; i < 2; i++) {
            const int gm0 = m_base + wr * 32 + i * 16 + lg * 4;
            #pragma unroll
            for (int r = 0; r < 4; r++) {
                float v = acc[i][j][r] + bv;
                stdelta(delta, (size_t)(gm0 + r) * DIN + gd, softplus_f(v));
            }
        }
    }
}

// ---------------- K3a: per-chunk local scan (h from 0), emit hend0 + S=sum(delta) ----------------
template <typename DT>
__global__ __launch_bounds__(256) void k3a_local(const float* __restrict__ x,
                                                 const DT* __restrict__ delta,
                                                 const float* __restrict__ xdbl,
                                                 const float* __restrict__ A_log,
                                                 float* __restrict__ Sbuf,
                                                 float* __restrict__ hend0) {
    const int tid = threadIdx.x;
    const int d = blockIdx.x * 256 + tid;
    const int c = blockIdx.y, b = blockIdx.z;

    float4 aq[4];
    #pragma unroll
    for (int q = 0; q < 4; q++) aq[q] = *reinterpret_cast<const float4*>(&A_log[d * NST + q * 4]);
    const float* av = reinterpret_cast<const float*>(aq);
    float A2[NST];
    #pragma unroll
    for (int n = 0; n < NST; n++) A2[n] = -expf(av[n]) * LOG2E;

    float h[NST];
    #pragma unroll
    for (int n = 0; n < NST; n++) h[n] = 0.f;
    float S = 0.f;

    const size_t gbase = (size_t)b * LSEQ * DIN + (size_t)c * LC * DIN + d;
    const float* Bbase = xdbl + ((size_t)b * LSEQ + (size_t)c * LC) * EOUT + RDT;

    float dv = lddelta(delta, gbase);
    float xv = x[gbase];
    float4 bq[4];
    {
        const float4* Bp = reinterpret_cast<const float4*>(Bbase);
        bq[0] = Bp[0]; bq[1] = Bp[1]; bq[2] = Bp[2]; bq[3] = Bp[3];
    }
    for (int tt = 0; tt < LC; tt++) {
        const int ttn = (tt + 1 < LC) ? tt + 1 : tt;
        float dv_n = lddelta(delta, gbase + (size_t)ttn * DIN);
        float xv_n = x[gbase + (size_t)ttn * DIN];
        float4 bqn[4];
        {
            const float4* Bp = reinterpret_cast<const float4*>(Bbase + (size_t)ttn * EOUT);
            bqn[0] = Bp[0]; bqn[1] = Bp[1]; bqn[2] = Bp[2]; bqn[3] = Bp[3];
        }
        const float* Bv = reinterpret_cast<const float*>(bq);
        S += dv;
        const float dvx = dv * xv;
        #pragma unroll
        for (int n = 0; n < NST; n++)
            h[n] = fmaf(__builtin_amdgcn_exp2f(dv * A2[n]), h[n], dvx * Bv[n]);
        dv = dv_n; xv = xv_n;
        bq[0] = bqn[0]; bq[1] = bqn[1]; bq[2] = bqn[2]; bq[3] = bqn[3];
    }
    Sbuf[((size_t)b * NC + c) * DIN + d] = S;
    float* hp = hend0 + (((size_t)b * NC + c) * DIN + d) * NST;
    #pragma unroll
    for (int q = 0; q < 4; q++)
        reinterpret_cast<float4*>(hp)[q] = make_float4(h[q*4], h[q*4+1], h[q*4+2], h[q*4+3]);
}

// ---------------- K3b: sequential chunk combine -> hinit per chunk ----------------
__global__ __launch_bounds__(256) void k3b_combine(const float* __restrict__ Sbuf,
                                                   const float* __restrict__ hend0,
                                                   const float* __restrict__ A_log,
                                                   float* __restrict__ hinit) {
    const int i = blockIdx.x * 256 + threadIdx.x;
    const int b = i / (DIN * NST);
    const int r = i % (DIN * NST);
    const int d = r >> 4;
    const float A2 = -expf(A_log[r]) * LOG2E;
    float hi = 0.f;
    for (int c = 0; c < NC; c++) {
        const size_t idx = ((size_t)b * NC + c) * DIN * NST + r;
        hinit[idx] = hi;
        hi = fmaf(__builtin_amdgcn_exp2f(Sbuf[((size_t)b * NC + c) * DIN + d] * A2), hi, hend0[idx]);
    }
}

// ---------------- K3c: per-chunk scan from hinit, emit y ----------------
template <typename DT>
__global__ __launch_bounds__(256) void k3c_scan(const float* __restrict__ x,
                                                const DT* __restrict__ delta,
                                                const float* __restrict__ xdbl,
                                                const float* __restrict__ A_log,
                                                const float* __restrict__ Dw,
                                                const float* __restrict__ hinit,
                                                float* __restrict__ out) {
    const int tid = threadIdx.x;
    const int d = blockIdx.x * 256 + tid;
    const int c = blockIdx.y, b = blockIdx.z;

    float4 aq[4];
    #pragma unroll
    for (int q = 0; q < 4; q++) aq[q] = *reinterpret_cast<const float4*>(&A_log[d * NST + q * 4]);
    const float* av = reinterpret_cast<const float*>(aq);
    float A2[NST];
    #pragma unroll
    for (int n = 0; n < NST; n++) A2[n] = -expf(av[n]) * LOG2E;

    float h[NST];
    {
        const float* hp = hinit + (((size_t)b * NC + c) * DIN + d) * NST;
        float4 hq[4];
        #pragma unroll
        for (int q = 0; q < 4; q++) hq[q] = reinterpret_cast<const float4*>(hp)[q];
        const float* hv = reinterpret_cast<const float*>(hq);
        #pragma unroll
        for (int n = 0; n < NST; n++) h[n] = hv[n];
    }
    const float Dv = Dw[d];

    const size_t gbase = (size_t)b * LSEQ * DIN + (size_t)c * LC * DIN + d;
    const float* Bbase = xdbl + ((size_t)b * LSEQ + (size_t)c * LC) * EOUT + RDT;

    float dv = lddelta(delta, gbase);
    float xv = x[gbase];
    float4 bq[4], cq[4];
    {
        const float4* Bp = reinterpret_cast<const float4*>(Bbase);
        bq[0] = Bp[0]; bq[1] = Bp[1]; bq[2] = Bp[2]; bq[3] = Bp[3];
        cq[0] = Bp[4]; cq[1] = Bp[5]; cq[2] = Bp[6]; cq[3] = Bp[7];
    }
    for (int tt = 0; tt < LC; tt++) {
        const int ttn = (tt + 1 < LC) ? tt + 1 : tt;
        float dv_n = lddelta(delta, gbase + (size_t)ttn * DIN);
        float xv_n = x[gbase + (size_t)ttn * DIN];
        float4 bqn[4], cqn[4];
        {
            const float4* Bp = reinterpret_cast<const float4*>(Bbase + (size_t)ttn * EOUT);
            bqn[0] = Bp[0]; bqn[1] = Bp[1]; bqn[2] = Bp[2]; bqn[3] = Bp[3];
            cqn[0] = Bp[4]; cqn[1] = Bp[5]; cqn[2] = Bp[6]; cqn[3] = Bp[7];
        }
        const float* Bv = reinterpret_cast<const float*>(bq);
        const float* Cv = reinterpret_cast<const float*>(cq);
        const float dvx = dv * xv;
        float y0 = 0.f, y1 = 0.f, y2 = 0.f, y3 = 0.f;
        #pragma unroll
        for (int n = 0; n < NST; n += 4) {
            h[n+0] = fmaf(__builtin_amdgcn_exp2f(dv * A2[n+0]), h[n+0], dvx * Bv[n+0]);
            y0 = fmaf(h[n+0], Cv[n+0], y0);
            h[n+1] = fmaf(__builtin_amdgcn_exp2f(dv * A2[n+1]), h[n+1], dvx * Bv[n+1]);
            y1 = fmaf(h[n+1], Cv[n+1], y1);
            h[n+2] = fmaf(__builtin_amdgcn_exp2f(dv * A2[n+2]), h[n+2], dvx * Bv[n+2]);
            y2 = fmaf(h[n+2], Cv[n+2], y2);
            h[n+3] = fmaf(__builtin_amdgcn_exp2f(dv * A2[n+3]), h[n+3], dvx * Bv[n+3]);
            y3 = fmaf(h[n+3], Cv[n+3], y3);
        }
        out[gbase + (size_t)tt * DIN] = ((y0 + y1) + (y2 + y3)) + xv * Dv;
        dv = dv_n; xv = xv_n;
        bq[0] = bqn[0]; bq[1] = bqn[1]; bq[2] = bqn[2]; bq[3] = bqn[3];
        cq[0] = cqn[0]; cq[1] = cqn[1]; cq[2] = cqn[2]; cq[3] = cqn[3];
    }
}

extern "C" void kernel_launch(void* const* d_in, const int* in_sizes, int n_in,
                              void* d_out, int out_size, void* d_ws, size_t ws_size,
                              hipStream_t stream) {
    const float* x     = (const float*)d_in[0];
    const float* A_log = (const float*)d_in[1];
    const float* Dw    = (const float*)d_in[2];
    const float* xpw   = (const float*)d_in[3];
    const float* dtw   = (const float*)d_in[4];
    const float* dtb   = (const float*)d_in[5];
    float* out = (float*)d_out;

    char* ws = (char*)d_ws;
    size_t off = 0;
    float* xdbl  = (float*)(ws + off); off += (size_t)MROWS * EOUT * 4;           // 3.15 MB
    float* hend0 = (float*)(ws + off); off += (size_t)BATCH * NC * DIN * NST * 4; // 20.97 MB
    float* hinit = (float*)(ws + off); off += (size_t)BATCH * NC * DIN * NST * 4; // 20.97 MB
    float* Sbuf  = (float*)(ws + off); off += (size_t)BATCH * NC * DIN * 4;       // 1.31 MB
    float* part = hend0;  // K1 partials alias hend0+hinit (dead until k3a)
    const size_t delta_off = off;
    const bool f32ok = ws_size >= delta_off + (size_t)MROWS * DIN * 4;

    k1_gemm<<<dim3(MROWS / K1_MT, K1_KSPLIT), 256, 0, stream>>>(x, xpw, part);
    k1_reduce<<<dim3(MROWS * EOUT / 4 / 256), 256, 0, stream>>>(part, xdbl);

    if (f32ok) {
        float* delta = (float*)(ws + delta_off);
        k2_mfma<float><<<dim3(MROWS / 64, DIN / 256), 256, 0, stream>>>(xdbl, dtw, dtb, delta);
        k3a_local<float><<<dim3(DIN / 256, NC, BATCH), 256, 0, stream>>>(x, delta, xdbl, A_log, Sbuf, hend0);
        k3b_combine<<<dim3(BATCH * DIN * NST / 256), 256, 0, stream>>>(Sbuf, hend0, A_log, hinit);
        k3c_scan<float><<<dim3(DIN / 256, NC, BATCH), 256, 0, stream>>>(x, delta, xdbl, A_log, Dw, hinit, out);
    } else {
        __hip_bfloat16* delta = (__hip_bfloat16*)(ws + delta_off);
        k2_mfma<__hip_bfloat16><<<dim3(MROWS / 64, DIN / 256), 256, 0, stream>>>(xdbl, dtw, dtb, delta);
        k3a_local<__hip_bfloat16><<<dim3(DIN / 256, NC, BATCH), 256, 0, stream>>>(x, delta, xdbl, A_log, Sbuf, hend0);
        k3b_combine<<<dim3(BATCH * DIN * NST / 256), 256, 0, stream>>>(Sbuf, hend0, A_log, hinit);
        k3c_scan<__hip_bfloat16><<<dim3(DIN / 256, NC, BATCH), 256, 0, stream>>>(x, delta, xdbl, A_log, Dw, hinit, out);
    }
}

// Round 4
// 304.451 us; speedup vs baseline: 2.7684x; 1.2241x over previous
//
#include <hip/hip_runtime.h>
#include <hip/hip_bf16.h>

#define DIN   5120
#define LSEQ  2048
#define BATCH 2
#define MROWS 4096      // BATCH*LSEQ
#define EOUT  192       // DT_RANK + 2N
#define RDT   160       // DT_RANK
#define NST   16
#define NC    32        // scan chunks
#define LC    64        // timesteps per chunk (NC*LC == LSEQ)
#define LOG2E 1.44269504088896f
#define LN2   0.69314718055995f

typedef __attribute__((ext_vector_type(8))) short bf16x8;
typedef __attribute__((ext_vector_type(4))) float f32x4;

// ---------------- helpers ----------------
__device__ __forceinline__ void stdelta(float* p, size_t i, float v) { p[i] = v; }
__device__ __forceinline__ void stdelta(__hip_bfloat16* p, size_t i, float v) { p[i] = __float2bfloat16(v); }
__device__ __forceinline__ float lddelta(const float* p, size_t i) { return p[i]; }
__device__ __forceinline__ float lddelta(const __hip_bfloat16* p, size_t i) { return __bfloat162float(p[i]); }

__device__ __forceinline__ float softplus_f(float v) {
    return fmaxf(v, 0.f) + log1pf(expf(-fabsf(v)));
}
// hw-trans softplus: ln(1+e^v) = max(v,0) + log2(1+2^(-|v|*log2e))*ln2
__device__ __forceinline__ float softplus_fast(float v) {
    float t = __builtin_amdgcn_exp2f(-fabsf(v) * LOG2E);
    return fmaxf(v, 0.f) + __builtin_amdgcn_logf(1.f + t) * LN2;
}
__device__ __forceinline__ unsigned short bf16rne(float f) {
    unsigned int u = __float_as_uint(f);
    unsigned int r = (u + 0x7FFFu + ((u >> 16) & 1u)) >> 16;
    return (unsigned short)r;
}

// ---------------- K0: w2 fp32 -> bf16 (RNE) ----------------
__global__ void k0_cvtw(const float* __restrict__ w2, ushort* __restrict__ bW) {
    int i = blockIdx.x * 256 + threadIdx.x;      // float4 idx, DIN*RDT/4 total
    float4 v = reinterpret_cast<const float4*>(w2)[i];
    ushort4 o = make_ushort4(bf16rne(v.x), bf16rne(v.y), bf16rne(v.z), bf16rne(v.w));
    reinterpret_cast<ushort4*>(bW)[i] = o;
}

// ---------------- K1: x_dbl partials = x @ x_proj_w^T (split-K) ----------------
#define K1_MT 64
#define K1_KC 64
#define K1_KSPLIT 8
__global__ __launch_bounds__(256, 2) void k1_gemm(const float* __restrict__ x,
                                                  const float* __restrict__ w,
                                                  float* __restrict__ part) {
    __shared__ float xs[K1_KC][K1_MT + 4];
    __shared__ float ws[K1_KC][EOUT + 4];
    const int tid = threadIdx.x;
    const int m_base = blockIdx.x * K1_MT;
    const int k_base = blockIdx.y * (DIN / K1_KSPLIT);
    const int mg = tid & 15;
    const int eg = tid >> 4;
    const int m0 = mg * 4, e0 = eg * 12;

    float acc[4][12];
    #pragma unroll
    for (int i = 0; i < 4; i++)
        #pragma unroll
        for (int j = 0; j < 12; j++) acc[i][j] = 0.f;

    for (int kc = 0; kc < (DIN / K1_KSPLIT); kc += K1_KC) {
        const int k0 = k_base + kc;
        {
            int f4i = tid;
            #pragma unroll
            for (int i = 0; i < 4; i++) {
                int m = f4i >> 4, kq = f4i & 15;
                float4 v = *reinterpret_cast<const float4*>(&x[(size_t)(m_base + m) * DIN + k0 + kq * 4]);
                xs[kq * 4 + 0][m] = v.x; xs[kq * 4 + 1][m] = v.y;
                xs[kq * 4 + 2][m] = v.z; xs[kq * 4 + 3][m] = v.w;
                f4i += 256;
            }
        }
        {
            int f4i = tid;
            #pragma unroll
            for (int i = 0; i < 12; i++) {
                int e = f4i >> 4, kq = f4i & 15;
                float4 v = *reinterpret_cast<const float4*>(&w[(size_t)e * DIN + k0 + kq * 4]);
                ws[kq * 4 + 0][e] = v.x; ws[kq * 4 + 1][e] = v.y;
                ws[kq * 4 + 2][e] = v.z; ws[kq * 4 + 3][e] = v.w;
                f4i += 256;
            }
        }
        __syncthreads();
        #pragma unroll 4
        for (int kk = 0; kk < K1_KC; kk++) {
            float4 xv = *reinterpret_cast<const float4*>(&xs[kk][m0]);
            float4 w0 = *reinterpret_cast<const float4*>(&ws[kk][e0]);
            float4 w1 = *reinterpret_cast<const float4*>(&ws[kk][e0 + 4]);
            float4 w2 = *reinterpret_cast<const float4*>(&ws[kk][e0 + 8]);
            float xr[4] = {xv.x, xv.y, xv.z, xv.w};
            float wr[12] = {w0.x, w0.y, w0.z, w0.w, w1.x, w1.y, w1.z, w1.w,
                            w2.x, w2.y, w2.z, w2.w};
            #pragma unroll
            for (int i = 0; i < 4; i++)
                #pragma unroll
                for (int j = 0; j < 12; j++) acc[i][j] = fmaf(xr[i], wr[j], acc[i][j]);
        }
        __syncthreads();
    }
    float* p = part + (size_t)blockIdx.y * MROWS * EOUT;
    #pragma unroll
    for (int i = 0; i < 4; i++) {
        size_t row = (size_t)(m_base + m0 + i) * EOUT + e0;
        *reinterpret_cast<float4*>(&p[row + 0]) = make_float4(acc[i][0], acc[i][1], acc[i][2], acc[i][3]);
        *reinterpret_cast<float4*>(&p[row + 4]) = make_float4(acc[i][4], acc[i][5], acc[i][6], acc[i][7]);
        *reinterpret_cast<float4*>(&p[row + 8]) = make_float4(acc[i][8], acc[i][9], acc[i][10], acc[i][11]);
    }
}

// reduce split-K partials; also emit dtraw (cols<160) as bf16 hi/lo (trunc/RNE pair)
__global__ void k1_reduce(const float* __restrict__ part, float* __restrict__ xdbl,
                          ushort* __restrict__ aHi, ushort* __restrict__ aLo) {
    int i = blockIdx.x * 256 + threadIdx.x;   // float4 idx over [MROWS][48]
    const float4* p = reinterpret_cast<const float4*>(part);
    float4 s = p[i];
    #pragma unroll
    for (int k = 1; k < K1_KSPLIT; k++) {
        float4 v = p[(size_t)k * (MROWS * EOUT / 4) + i];
        s.x += v.x; s.y += v.y; s.z += v.z; s.w += v.w;
    }
    reinterpret_cast<float4*>(xdbl)[i] = s;
    int row = i / 48, e4 = i % 48;
    if (e4 < 40) {
        unsigned int hx = __float_as_uint(s.x) & 0xFFFF0000u;
        unsigned int hy = __float_as_uint(s.y) & 0xFFFF0000u;
        unsigned int hz = __float_as_uint(s.z) & 0xFFFF0000u;
        unsigned int hw = __float_as_uint(s.w) & 0xFFFF0000u;
        ushort4 hv = make_ushort4((unsigned short)(hx >> 16), (unsigned short)(hy >> 16),
                                  (unsigned short)(hz >> 16), (unsigned short)(hw >> 16));
        ushort4 lv = make_ushort4(bf16rne(s.x - __uint_as_float(hx)),
                                  bf16rne(s.y - __uint_as_float(hy)),
                                  bf16rne(s.z - __uint_as_float(hz)),
                                  bf16rne(s.w - __uint_as_float(hw)));
        *reinterpret_cast<ushort4*>(&aHi[(size_t)row * RDT + e4 * 4]) = hv;
        *reinterpret_cast<ushort4*>(&aLo[(size_t)row * RDT + e4 * 4]) = lv;
    }
}

// ---------------- K2 (MFMA, no LDS): delta = softplus(dtraw @ w2^T + b) ----------------
// M=4096 N=5120 K=160. Block 256 thr = 2x2 waves; block tile 64m x 256d;
// wave tile 32m x 128d. Fragments straight from L2-resident bf16 arrays.
// A split hi+lo (2-pass) for near-fp32 A precision; B single bf16 RNE.
template <typename DT>
__global__ __launch_bounds__(256, 3) void k2_mfma(const ushort* __restrict__ aHi,
                                                  const ushort* __restrict__ aLo,
                                                  const ushort* __restrict__ bW,
                                                  const float* __restrict__ bias,
                                                  DT* __restrict__ delta) {
    const int tid = threadIdx.x;
    const int m_base = blockIdx.x * 64, d_base = blockIdx.y * 256;
    const int lane = tid & 63, w = tid >> 6;
    const int wr = w >> 1, wc = w & 1;
    const int lr = lane & 15, lg = lane >> 4;

    f32x4 acc[2][8];
    #pragma unroll
    for (int i = 0; i < 2; i++)
        #pragma unroll
        for (int j = 0; j < 8; j++) acc[i][j] = (f32x4)(0.f);

    const size_t arow = (size_t)(m_base + wr * 32 + lr) * RDT;
    const size_t brow = (size_t)(d_base + wc * 128 + lr) * RDT;

    #pragma unroll
    for (int kk = 0; kk < 5; kk++) {
        const int ko = kk * 32 + lg * 8;
        bf16x8 ah0 = *reinterpret_cast<const bf16x8*>(aHi + arow + ko);
        bf16x8 ah1 = *reinterpret_cast<const bf16x8*>(aHi + arow + 16 * RDT + ko);
        bf16x8 al0 = *reinterpret_cast<const bf16x8*>(aLo + arow + ko);
        bf16x8 al1 = *reinterpret_cast<const bf16x8*>(aLo + arow + 16 * RDT + ko);
        #pragma unroll
        for (int j = 0; j < 8; j++) {
            bf16x8 bb = *reinterpret_cast<const bf16x8*>(bW + brow + (size_t)j * 16 * RDT + ko);
            acc[0][j] = __builtin_amdgcn_mfma_f32_16x16x32_bf16(ah0, bb, acc[0][j], 0, 0, 0);
            acc[1][j] = __builtin_amdgcn_mfma_f32_16x16x32_bf16(ah1, bb, acc[1][j], 0, 0, 0);
            acc[0][j] = __builtin_amdgcn_mfma_f32_16x16x32_bf16(al0, bb, acc[0][j], 0, 0, 0);
            acc[1][j] = __builtin_amdgcn_mfma_f32_16x16x32_bf16(al1, bb, acc[1][j], 0, 0, 0);
        }
    }

    #pragma unroll
    for (int j = 0; j < 8; j++) {
        const int gd = d_base + wc * 128 + j * 16 + lr;
        const float bv = bias[gd];
        #pragma unroll
        for (int i = 0; i < 2; i++) {
            const int gm0 = m_base + wr * 32 + i * 16 + lg * 4;
            #pragma unroll
            for (int r = 0; r < 4; r++) {
                float v = acc[i][j][r] + bv;
                stdelta(delta, (size_t)(gm0 + r) * DIN + gd, softplus_fast(v));
            }
        }
    }
}

// ---------------- K3a: per-chunk local scan (h from 0), emit hend0 + S ----------------
template <typename DT>
__global__ __launch_bounds__(256) void k3a_local(const float* __restrict__ x,
                                                 const DT* __restrict__ delta,
                                                 const float* __restrict__ xdbl,
                                                 const float* __restrict__ A_log,
                                                 float* __restrict__ Sbuf,
                                                 float* __restrict__ hend0) {
    const int tid = threadIdx.x;
    const int d = blockIdx.x * 256 + tid;
    const int c = blockIdx.y, b = blockIdx.z;

    float4 aq[4];
    #pragma unroll
    for (int q = 0; q < 4; q++) aq[q] = *reinterpret_cast<const float4*>(&A_log[d * NST + q * 4]);
    const float* av = reinterpret_cast<const float*>(aq);
    float A2[NST];
    #pragma unroll
    for (int n = 0; n < NST; n++) A2[n] = -expf(av[n]) * LOG2E;

    float h[NST];
    #pragma unroll
    for (int n = 0; n < NST; n++) h[n] = 0.f;
    float S = 0.f;

    const size_t gbase = (size_t)b * LSEQ * DIN + (size_t)c * LC * DIN + d;
    const float* Bbase = xdbl + ((size_t)b * LSEQ + (size_t)c * LC) * EOUT + RDT;

    float dv = lddelta(delta, gbase);
    float xv = x[gbase];
    float4 bq[4];
    {
        const float4* Bp = reinterpret_cast<const float4*>(Bbase);
        bq[0] = Bp[0]; bq[1] = Bp[1]; bq[2] = Bp[2]; bq[3] = Bp[3];
    }
    for (int tt = 0; tt < LC; tt++) {
        const int ttn = (tt + 1 < LC) ? tt + 1 : tt;
        float dv_n = lddelta(delta, gbase + (size_t)ttn * DIN);
        float xv_n = x[gbase + (size_t)ttn * DIN];
        float4 bqn[4];
        {
            const float4* Bp = reinterpret_cast<const float4*>(Bbase + (size_t)ttn * EOUT);
            bqn[0] = Bp[0]; bqn[1] = Bp[1]; bqn[2] = Bp[2]; bqn[3] = Bp[3];
        }
        const float* Bv = reinterpret_cast<const float*>(bq);
        S += dv;
        const float dvx = dv * xv;
        #pragma unroll
        for (int n = 0; n < NST; n++)
            h[n] = fmaf(__builtin_amdgcn_exp2f(dv * A2[n]), h[n], dvx * Bv[n]);
        dv = dv_n; xv = xv_n;
        bq[0] = bqn[0]; bq[1] = bqn[1]; bq[2] = bqn[2]; bq[3] = bqn[3];
    }
    Sbuf[((size_t)b * NC + c) * DIN + d] = S;
    float* hp = hend0 + (((size_t)b * NC + c) * DIN + d) * NST;
    #pragma unroll
    for (int q = 0; q < 4; q++)
        reinterpret_cast<float4*>(hp)[q] = make_float4(h[q*4], h[q*4+1], h[q*4+2], h[q*4+3]);
}

// ---------------- K3b: sequential chunk combine -> hinit per chunk ----------------
__global__ __launch_bounds__(256) void k3b_combine(const float* __restrict__ Sbuf,
                                                   const float* __restrict__ hend0,
                                                   const float* __restrict__ A_log,
                                                   float* __restrict__ hinit) {
    const int i = blockIdx.x * 256 + threadIdx.x;
    const int b = i / (DIN * NST);
    const int r = i % (DIN * NST);
    const int d = r >> 4;
    const float A2 = -expf(A_log[r]) * LOG2E;
    float hi = 0.f;
    for (int c = 0; c < NC; c++) {
        const size_t idx = ((size_t)b * NC + c) * DIN * NST + r;
        hinit[idx] = hi;
        hi = fmaf(__builtin_amdgcn_exp2f(Sbuf[((size_t)b * NC + c) * DIN + d] * A2), hi, hend0[idx]);
    }
}

// ---------------- K3c: per-chunk scan from hinit, emit y ----------------
template <typename DT>
__global__ __launch_bounds__(256) void k3c_scan(const float* __restrict__ x,
                                                const DT* __restrict__ delta,
                                                const float* __restrict__ xdbl,
                                                const float* __restrict__ A_log,
                                                const float* __restrict__ Dw,
                                                const float* __restrict__ hinit,
                                                float* __restrict__ out) {
    const int tid = threadIdx.x;
    const int d = blockIdx.x * 256 + tid;
    const int c = blockIdx.y, b = blockIdx.z;

    float4 aq[4];
    #pragma unroll
    for (int q = 0; q < 4; q++) aq[q] = *reinterpret_cast<const float4*>(&A_log[d * NST + q * 4]);
    const float* av = reinterpret_cast<const float*>(aq);
    float A2[NST];
    #pragma unroll
    for (int n = 0; n < NST; n++) A2[n] = -expf(av[n]) * LOG2E;

    float h[NST];
    {
        const float* hp = hinit + (((size_t)b * NC + c) * DIN + d) * NST;
        float4 hq[4];
        #pragma unroll
        for (int q = 0; q < 4; q++) hq[q] = reinterpret_cast<const float4*>(hp)[q];
        const float* hv = reinterpret_cast<const float*>(hq);
        #pragma unroll
        for (int n = 0; n < NST; n++) h[n] = hv[n];
    }
    const float Dv = Dw[d];

    const size_t gbase = (size_t)b * LSEQ * DIN + (size_t)c * LC * DIN + d;
    const float* Bbase = xdbl + ((size_t)b * LSEQ + (size_t)c * LC) * EOUT + RDT;

    float dv = lddelta(delta, gbase);
    float xv = x[gbase];
    float4 bq[4], cq[4];
    {
        const float4* Bp = reinterpret_cast<const float4*>(Bbase);
        bq[0] = Bp[0]; bq[1] = Bp[1]; bq[2] = Bp[2]; bq[3] = Bp[3];
        cq[0] = Bp[4]; cq[1] = Bp[5]; cq[2] = Bp[6]; cq[3] = Bp[7];
    }
    for (int tt = 0; tt < LC; tt++) {
        const int ttn = (tt + 1 < LC) ? tt + 1 : tt;
        float dv_n = lddelta(delta, gbase + (size_t)ttn * DIN);
        float xv_n = x[gbase + (size_t)ttn * DIN];
        float4 bqn[4], cqn[4];
        {
            const float4* Bp = reinterpret_cast<const float4*>(Bbase + (size_t)ttn * EOUT);
            bqn[0] = Bp[0]; bqn[1] = Bp[1]; bqn[2] = Bp[2]; bqn[3] = Bp[3];
            cqn[0] = Bp[4]; cqn[1] = Bp[5]; cqn[2] = Bp[6]; cqn[3] = Bp[7];
        }
        const float* Bv = reinterpret_cast<const float*>(bq);
        const float* Cv = reinterpret_cast<const float*>(cq);
        const float dvx = dv * xv;
        float y0 = 0.f, y1 = 0.f, y2 = 0.f, y3 = 0.f;
        #pragma unroll
        for (int n = 0; n < NST; n += 4) {
            h[n+0] = fmaf(__builtin_amdgcn_exp2f(dv * A2[n+0]), h[n+0], dvx * Bv[n+0]);
            y0 = fmaf(h[n+0], Cv[n+0], y0);
            h[n+1] = fmaf(__builtin_amdgcn_exp2f(dv * A2[n+1]), h[n+1], dvx * Bv[n+1]);
            y1 = fmaf(h[n+1], Cv[n+1], y1);
            h[n+2] = fmaf(__builtin_amdgcn_exp2f(dv * A2[n+2]), h[n+2], dvx * Bv[n+2]);
            y2 = fmaf(h[n+2], Cv[n+2], y2);
            h[n+3] = fmaf(__builtin_amdgcn_exp2f(dv * A2[n+3]), h[n+3], dvx * Bv[n+3]);
            y3 = fmaf(h[n+3], Cv[n+3], y3);
        }
        out[gbase + (size_t)tt * DIN] = ((y0 + y1) + (y2 + y3)) + xv * Dv;
        dv = dv_n; xv = xv_n;
        bq[0] = bqn[0]; bq[1] = bqn[1]; bq[2] = bqn[2]; bq[3] = bqn[3];
        cq[0] = cqn[0]; cq[1] = cqn[1]; cq[2] = cqn[2]; cq[3] = cqn[3];
    }
}

extern "C" void kernel_launch(void* const* d_in, const int* in_sizes, int n_in,
                              void* d_out, int out_size, void* d_ws, size_t ws_size,
                              hipStream_t stream) {
    const float* x     = (const float*)d_in[0];
    const float* A_log = (const float*)d_in[1];
    const float* Dw    = (const float*)d_in[2];
    const float* xpw   = (const float*)d_in[3];
    const float* dtw   = (const float*)d_in[4];
    const float* dtb   = (const float*)d_in[5];
    float* out = (float*)d_out;

    char* ws = (char*)d_ws;
    size_t off = 0;
    float* xdbl  = (float*)(ws + off); off += (size_t)MROWS * EOUT * 4;           // 3.15 MB
    float* hend0 = (float*)(ws + off); off += (size_t)BATCH * NC * DIN * NST * 4; // 20.97 MB
    float* hinit = (float*)(ws + off); off += (size_t)BATCH * NC * DIN * NST * 4; // 20.97 MB
    float* Sbuf  = (float*)(ws + off); off += (size_t)BATCH * NC * DIN * 4;       // 1.31 MB
    ushort* aHi  = (ushort*)(ws + off); off += (size_t)MROWS * RDT * 2;           // 1.31 MB
    ushort* aLo  = (ushort*)(ws + off); off += (size_t)MROWS * RDT * 2;           // 1.31 MB
    ushort* bW   = (ushort*)(ws + off); off += (size_t)DIN * RDT * 2;             // 1.64 MB
    float* part = hend0;  // K1 partials alias hend0+hinit (dead until k3a)
    const size_t delta_off = off;
    const bool f32ok = ws_size >= delta_off + (size_t)MROWS * DIN * 4;

    k0_cvtw<<<dim3(DIN * RDT / 4 / 256), 256, 0, stream>>>(dtw, bW);
    k1_gemm<<<dim3(MROWS / K1_MT, K1_KSPLIT), 256, 0, stream>>>(x, xpw, part);
    k1_reduce<<<dim3(MROWS * EOUT / 4 / 256), 256, 0, stream>>>(part, xdbl, aHi, aLo);

    if (f32ok) {
        float* delta = (float*)(ws + delta_off);
        k2_mfma<float><<<dim3(MROWS / 64, DIN / 256), 256, 0, stream>>>(aHi, aLo, bW, dtb, delta);
        k3a_local<float><<<dim3(DIN / 256, NC, BATCH), 256, 0, stream>>>(x, delta, xdbl, A_log, Sbuf, hend0);
        k3b_combine<<<dim3(BATCH * DIN * NST / 256), 256, 0, stream>>>(Sbuf, hend0, A_log, hinit);
        k3c_scan<float><<<dim3(DIN / 256, NC, BATCH), 256, 0, stream>>>(x, delta, xdbl, A_log, Dw, hinit, out);
    } else {
        __hip_bfloat16* delta = (__hip_bfloat16*)(ws + delta_off);
        k2_mfma<__hip_bfloat16><<<dim3(MROWS / 64, DIN / 256), 256, 0, stream>>>(aHi, aLo, bW, dtb, delta);
        k3a_local<__hip_bfloat16><<<dim3(DIN / 256, NC, BATCH), 256, 0, stream>>>(x, delta, xdbl, A_log, Sbuf, hend0);
        k3b_combine<<<dim3(BATCH * DIN * NST / 256), 256, 0, stream>>>(Sbuf, hend0, A_log, hinit);
        k3c_scan<__hip_bfloat16><<<dim3(DIN / 256, NC, BATCH), 256, 0, stream>>>(x, delta, xdbl, A_log, Dw, hinit, out);
    }
}

// Round 5
// 240.993 us; speedup vs baseline: 3.4974x; 1.2633x over previous
//
#include <hip/hip_runtime.h>
#include <hip/hip_bf16.h>

#define DIN   5120
#define LSEQ  2048
#define BATCH 2
#define MROWS 4096      // BATCH*LSEQ
#define EOUT  192       // DT_RANK + 2N
#define RDT   160       // DT_RANK
#define NST   16
#define NC    32        // scan chunks
#define LC    64        // timesteps per chunk (NC*LC == LSEQ)
#define LOG2E 1.44269504088896f
#define LN2   0.69314718055995f

typedef __attribute__((ext_vector_type(8))) short bf16x8;
typedef __attribute__((ext_vector_type(4))) float f32x4;

// ---------------- helpers ----------------
__device__ __forceinline__ void stdelta(float* p, size_t i, float v) { p[i] = v; }
__device__ __forceinline__ void stdelta(__hip_bfloat16* p, size_t i, float v) { p[i] = __float2bfloat16(v); }
__device__ __forceinline__ float lddelta(const float* p, size_t i) { return p[i]; }
__device__ __forceinline__ float lddelta(const __hip_bfloat16* p, size_t i) { return __bfloat162float(p[i]); }

// hw-trans softplus: ln(1+e^v) = max(v,0) + log2(1+2^(-|v|*log2e))*ln2
__device__ __forceinline__ float softplus_fast(float v) {
    float t = __builtin_amdgcn_exp2f(-fabsf(v) * LOG2E);
    return fmaxf(v, 0.f) + __builtin_amdgcn_logf(1.f + t) * LN2;
}
__device__ __forceinline__ unsigned short bf16rne(float f) {
    unsigned int u = __float_as_uint(f);
    unsigned int r = (u + 0x7FFFu + ((u >> 16) & 1u)) >> 16;
    return (unsigned short)r;
}
// 8 fp32 -> bf16 hi (trunc) + lo (rne of residual)
__device__ __forceinline__ void cvt8(float4 a, float4 b, bf16x8& h, bf16x8& l) {
    float v[8] = {a.x, a.y, a.z, a.w, b.x, b.y, b.z, b.w};
    #pragma unroll
    for (int e = 0; e < 8; e++) {
        unsigned int u = __float_as_uint(v[e]);
        unsigned int hb = u & 0xFFFF0000u;
        h[e] = (short)(hb >> 16);
        l[e] = (short)bf16rne(v[e] - __uint_as_float(hb));
    }
}

// ---------------- K0: fp32 -> bf16 (RNE) converter ----------------
__global__ void k0_cvtw(const float* __restrict__ w, ushort* __restrict__ bw) {
    int i = blockIdx.x * 256 + threadIdx.x;
    float4 v = reinterpret_cast<const float4*>(w)[i];
    ushort4 o = make_ushort4(bf16rne(v.x), bf16rne(v.y), bf16rne(v.z), bf16rne(v.w));
    reinterpret_cast<ushort4*>(bw)[i] = o;
}

// ---------------- K1 (MFMA, no LDS): x_dbl partials = x @ x_proj_w^T ----------------
// M=4096 N=192 K=5120, split-K. Block 256 thr = 4 waves stacked in m:
// block tile 128m x 192e, wave tile 32m x 192e. A = x fp32 -> in-reg hi/lo
// bf16 (2-pass); B = pre-converted bf16 RNE w (L2-resident).
template <int KPS>   // k-elements per split
__global__ __launch_bounds__(256) void k1_mfma(const float* __restrict__ x,
                                               const ushort* __restrict__ bWp,
                                               float* __restrict__ part) {
    const int tid = threadIdx.x;
    const int m_base = blockIdx.x * 128;
    const int k_base = blockIdx.y * KPS;
    const int lane = tid & 63, w = tid >> 6;
    const int lr = lane & 15, lg = lane >> 4;
    const int wm = m_base + w * 32;

    f32x4 acc[2][12];
    #pragma unroll
    for (int i = 0; i < 2; i++)
        #pragma unroll
        for (int j = 0; j < 12; j++) acc[i][j] = (f32x4)(0.f);

    const float* xr0 = x + (size_t)(wm + lr) * DIN + k_base;
    const float* xr1 = x + (size_t)(wm + 16 + lr) * DIN + k_base;

    #pragma unroll 2
    for (int kk = 0; kk < KPS / 32; kk++) {
        const int ko = kk * 32 + lg * 8;
        float4 v0 = *reinterpret_cast<const float4*>(xr0 + ko);
        float4 v1 = *reinterpret_cast<const float4*>(xr0 + ko + 4);
        float4 v2 = *reinterpret_cast<const float4*>(xr1 + ko);
        float4 v3 = *reinterpret_cast<const float4*>(xr1 + ko + 4);
        bf16x8 ah0, al0, ah1, al1;
        cvt8(v0, v1, ah0, al0);
        cvt8(v2, v3, ah1, al1);
        #pragma unroll
        for (int j = 0; j < 12; j++) {
            bf16x8 bb = *reinterpret_cast<const bf16x8*>(bWp + (size_t)(j * 16 + lr) * DIN + k_base + ko);
            acc[0][j] = __builtin_amdgcn_mfma_f32_16x16x32_bf16(ah0, bb, acc[0][j], 0, 0, 0);
            acc[1][j] = __builtin_amdgcn_mfma_f32_16x16x32_bf16(ah1, bb, acc[1][j], 0, 0, 0);
            acc[0][j] = __builtin_amdgcn_mfma_f32_16x16x32_bf16(al0, bb, acc[0][j], 0, 0, 0);
            acc[1][j] = __builtin_amdgcn_mfma_f32_16x16x32_bf16(al1, bb, acc[1][j], 0, 0, 0);
        }
    }
    float* p = part + (size_t)blockIdx.y * MROWS * EOUT;
    #pragma unroll
    for (int j = 0; j < 12; j++) {
        const int e = j * 16 + lr;
        #pragma unroll
        for (int i = 0; i < 2; i++) {
            const int m0 = wm + i * 16 + lg * 4;
            #pragma unroll
            for (int r = 0; r < 4; r++)
                p[(size_t)(m0 + r) * EOUT + e] = acc[i][j][r];
        }
    }
}

// reduce split-K partials; emit xdbl fp32 + dtraw (cols<160) as bf16 hi/lo
template <int KS>
__global__ void k1_reduce(const float* __restrict__ part, float* __restrict__ xdbl,
                          ushort* __restrict__ aHi, ushort* __restrict__ aLo) {
    int i = blockIdx.x * 256 + threadIdx.x;   // float4 idx over [MROWS][48]
    const float4* p = reinterpret_cast<const float4*>(part);
    float4 s = p[i];
    #pragma unroll
    for (int k = 1; k < KS; k++) {
        float4 v = p[(size_t)k * (MROWS * EOUT / 4) + i];
        s.x += v.x; s.y += v.y; s.z += v.z; s.w += v.w;
    }
    reinterpret_cast<float4*>(xdbl)[i] = s;
    int row = i / 48, e4 = i % 48;
    if (e4 < 40) {
        unsigned int hx = __float_as_uint(s.x) & 0xFFFF0000u;
        unsigned int hy = __float_as_uint(s.y) & 0xFFFF0000u;
        unsigned int hz = __float_as_uint(s.z) & 0xFFFF0000u;
        unsigned int hw = __float_as_uint(s.w) & 0xFFFF0000u;
        ushort4 hv = make_ushort4((unsigned short)(hx >> 16), (unsigned short)(hy >> 16),
                                  (unsigned short)(hz >> 16), (unsigned short)(hw >> 16));
        ushort4 lv = make_ushort4(bf16rne(s.x - __uint_as_float(hx)),
                                  bf16rne(s.y - __uint_as_float(hy)),
                                  bf16rne(s.z - __uint_as_float(hz)),
                                  bf16rne(s.w - __uint_as_float(hw)));
        *reinterpret_cast<ushort4*>(&aHi[(size_t)row * RDT + e4 * 4]) = hv;
        *reinterpret_cast<ushort4*>(&aLo[(size_t)row * RDT + e4 * 4]) = lv;
    }
}

// ---------------- K2 (MFMA, no LDS): delta = softplus(dtraw @ w2^T + b) ----------------
template <typename DT>
__global__ __launch_bounds__(256, 3) void k2_mfma(const ushort* __restrict__ aHi,
                                                  const ushort* __restrict__ aLo,
                                                  const ushort* __restrict__ bW,
                                                  const float* __restrict__ bias,
                                                  DT* __restrict__ delta) {
    const int tid = threadIdx.x;
    const int m_base = blockIdx.x * 64, d_base = blockIdx.y * 256;
    const int lane = tid & 63, w = tid >> 6;
    const int wr = w >> 1, wc = w & 1;
    const int lr = lane & 15, lg = lane >> 4;

    f32x4 acc[2][8];
    #pragma unroll
    for (int i = 0; i < 2; i++)
        #pragma unroll
        for (int j = 0; j < 8; j++) acc[i][j] = (f32x4)(0.f);

    const size_t arow = (size_t)(m_base + wr * 32 + lr) * RDT;
    const size_t brow = (size_t)(d_base + wc * 128 + lr) * RDT;

    #pragma unroll
    for (int kk = 0; kk < 5; kk++) {
        const int ko = kk * 32 + lg * 8;
        bf16x8 ah0 = *reinterpret_cast<const bf16x8*>(aHi + arow + ko);
        bf16x8 ah1 = *reinterpret_cast<const bf16x8*>(aHi + arow + 16 * RDT + ko);
        bf16x8 al0 = *reinterpret_cast<const bf16x8*>(aLo + arow + ko);
        bf16x8 al1 = *reinterpret_cast<const bf16x8*>(aLo + arow + 16 * RDT + ko);
        #pragma unroll
        for (int j = 0; j < 8; j++) {
            bf16x8 bb = *reinterpret_cast<const bf16x8*>(bW + brow + (size_t)j * 16 * RDT + ko);
            acc[0][j] = __builtin_amdgcn_mfma_f32_16x16x32_bf16(ah0, bb, acc[0][j], 0, 0, 0);
            acc[1][j] = __builtin_amdgcn_mfma_f32_16x16x32_bf16(ah1, bb, acc[1][j], 0, 0, 0);
            acc[0][j] = __builtin_amdgcn_mfma_f32_16x16x32_bf16(al0, bb, acc[0][j], 0, 0, 0);
            acc[1][j] = __builtin_amdgcn_mfma_f32_16x16x32_bf16(al1, bb, acc[1][j], 0, 0, 0);
        }
    }

    #pragma unroll
    for (int j = 0; j < 8; j++) {
        const int gd = d_base + wc * 128 + j * 16 + lr;
        const float bv = bias[gd];
        #pragma unroll
        for (int i = 0; i < 2; i++) {
            const int gm0 = m_base + wr * 32 + i * 16 + lg * 4;
            #pragma unroll
            for (int r = 0; r < 4; r++) {
                float v = acc[i][j][r] + bv;
                stdelta(delta, (size_t)(gm0 + r) * DIN + gd, softplus_fast(v));
            }
        }
    }
}

// ---------------- K3a: per-chunk local scan (h from 0), emit hend0 + S ----------------
template <typename DT>
__global__ __launch_bounds__(256) void k3a_local(const float* __restrict__ x,
                                                 const DT* __restrict__ delta,
                                                 const float* __restrict__ xdbl,
                                                 const float* __restrict__ A_log,
                                                 float* __restrict__ Sbuf,
                                                 float* __restrict__ hend0) {
    const int tid = threadIdx.x;
    const int d = blockIdx.x * 256 + tid;
    const int c = blockIdx.y, b = blockIdx.z;

    float4 aq[4];
    #pragma unroll
    for (int q = 0; q < 4; q++) aq[q] = *reinterpret_cast<const float4*>(&A_log[d * NST + q * 4]);
    const float* av = reinterpret_cast<const float*>(aq);
    float A2[NST];
    #pragma unroll
    for (int n = 0; n < NST; n++) A2[n] = -expf(av[n]) * LOG2E;

    float h[NST];
    #pragma unroll
    for (int n = 0; n < NST; n++) h[n] = 0.f;
    float S = 0.f;

    const size_t gbase = (size_t)b * LSEQ * DIN + (size_t)c * LC * DIN + d;
    const float* Bbase = xdbl + ((size_t)b * LSEQ + (size_t)c * LC) * EOUT + RDT;

    float dv = lddelta(delta, gbase);
    float xv = x[gbase];
    float4 bq[4];
    {
        const float4* Bp = reinterpret_cast<const float4*>(Bbase);
        bq[0] = Bp[0]; bq[1] = Bp[1]; bq[2] = Bp[2]; bq[3] = Bp[3];
    }
    for (int tt = 0; tt < LC; tt++) {
        const int ttn = (tt + 1 < LC) ? tt + 1 : tt;
        float dv_n = lddelta(delta, gbase + (size_t)ttn * DIN);
        float xv_n = x[gbase + (size_t)ttn * DIN];
        float4 bqn[4];
        {
            const float4* Bp = reinterpret_cast<const float4*>(Bbase + (size_t)ttn * EOUT);
            bqn[0] = Bp[0]; bqn[1] = Bp[1]; bqn[2] = Bp[2]; bqn[3] = Bp[3];
        }
        const float* Bv = reinterpret_cast<const float*>(bq);
        S += dv;
        const float dvx = dv * xv;
        #pragma unroll
        for (int n = 0; n < NST; n++)
            h[n] = fmaf(__builtin_amdgcn_exp2f(dv * A2[n]), h[n], dvx * Bv[n]);
        dv = dv_n; xv = xv_n;
        bq[0] = bqn[0]; bq[1] = bqn[1]; bq[2] = bqn[2]; bq[3] = bqn[3];
    }
    Sbuf[((size_t)b * NC + c) * DIN + d] = S;
    float* hp = hend0 + (((size_t)b * NC + c) * DIN + d) * NST;
    #pragma unroll
    for (int q = 0; q < 4; q++)
        reinterpret_cast<float4*>(hp)[q] = make_float4(h[q*4], h[q*4+1], h[q*4+2], h[q*4+3]);
}

// ---------------- K3b: sequential chunk combine -> hinit per chunk ----------------
__global__ __launch_bounds__(256) void k3b_combine(const float* __restrict__ Sbuf,
                                                   const float* __restrict__ hend0,
                                                   const float* __restrict__ A_log,
                                                   float* __restrict__ hinit) {
    const int i = blockIdx.x * 256 + threadIdx.x;
    const int b = i / (DIN * NST);
    const int r = i % (DIN * NST);
    const int d = r >> 4;
    const float A2 = -expf(A_log[r]) * LOG2E;
    float hi = 0.f;
    for (int c = 0; c < NC; c++) {
        const size_t idx = ((size_t)b * NC + c) * DIN * NST + r;
        hinit[idx] = hi;
        hi = fmaf(__builtin_amdgcn_exp2f(Sbuf[((size_t)b * NC + c) * DIN + d] * A2), hi, hend0[idx]);
    }
}

// ---------------- K3c: per-chunk scan from hinit, emit y ----------------
template <typename DT>
__global__ __launch_bounds__(256) void k3c_scan(const float* __restrict__ x,
                                                const DT* __restrict__ delta,
                                                const float* __restrict__ xdbl,
                                                const float* __restrict__ A_log,
                                                const float* __restrict__ Dw,
                                                const float* __restrict__ hinit,
                                                float* __restrict__ out) {
    const int tid = threadIdx.x;
    const int d = blockIdx.x * 256 + tid;
    const int c = blockIdx.y, b = blockIdx.z;

    float4 aq[4];
    #pragma unroll
    for (int q = 0; q < 4; q++) aq[q] = *reinterpret_cast<const float4*>(&A_log[d * NST + q * 4]);
    const float* av = reinterpret_cast<const float*>(aq);
    float A2[NST];
    #pragma unroll
    for (int n = 0; n < NST; n++) A2[n] = -expf(av[n]) * LOG2E;

    float h[NST];
    {
        const float* hp = hinit + (((size_t)b * NC + c) * DIN + d) * NST;
        float4 hq[4];
        #pragma unroll
        for (int q = 0; q < 4; q++) hq[q] = reinterpret_cast<const float4*>(hp)[q];
        const float* hv = reinterpret_cast<const float*>(hq);
        #pragma unroll
        for (int n = 0; n < NST; n++) h[n] = hv[n];
    }
    const float Dv = Dw[d];

    const size_t gbase = (size_t)b * LSEQ * DIN + (size_t)c * LC * DIN + d;
    const float* Bbase = xdbl + ((size_t)b * LSEQ + (size_t)c * LC) * EOUT + RDT;

    float dv = lddelta(delta, gbase);
    float xv = x[gbase];
    float4 bq[4], cq[4];
    {
        const float4* Bp = reinterpret_cast<const float4*>(Bbase);
        bq[0] = Bp[0]; bq[1] = Bp[1]; bq[2] = Bp[2]; bq[3] = Bp[3];
        cq[0] = Bp[4]; cq[1] = Bp[5]; cq[2] = Bp[6]; cq[3] = Bp[7];
    }
    for (int tt = 0; tt < LC; tt++) {
        const int ttn = (tt + 1 < LC) ? tt + 1 : tt;
        float dv_n = lddelta(delta, gbase + (size_t)ttn * DIN);
        float xv_n = x[gbase + (size_t)ttn * DIN];
        float4 bqn[4], cqn[4];
        {
            const float4* Bp = reinterpret_cast<const float4*>(Bbase + (size_t)ttn * EOUT);
            bqn[0] = Bp[0]; bqn[1] = Bp[1]; bqn[2] = Bp[2]; bqn[3] = Bp[3];
            cqn[0] = Bp[4]; cqn[1] = Bp[5]; cqn[2] = Bp[6]; cqn[3] = Bp[7];
        }
        const float* Bv = reinterpret_cast<const float*>(bq);
        const float* Cv = reinterpret_cast<const float*>(cq);
        const float dvx = dv * xv;
        float y0 = 0.f, y1 = 0.f, y2 = 0.f, y3 = 0.f;
        #pragma unroll
        for (int n = 0; n < NST; n += 4) {
            h[n+0] = fmaf(__builtin_amdgcn_exp2f(dv * A2[n+0]), h[n+0], dvx * Bv[n+0]);
            y0 = fmaf(h[n+0], Cv[n+0], y0);
            h[n+1] = fmaf(__builtin_amdgcn_exp2f(dv * A2[n+1]), h[n+1], dvx * Bv[n+1]);
            y1 = fmaf(h[n+1], Cv[n+1], y1);
            h[n+2] = fmaf(__builtin_amdgcn_exp2f(dv * A2[n+2]), h[n+2], dvx * Bv[n+2]);
            y2 = fmaf(h[n+2], Cv[n+2], y2);
            h[n+3] = fmaf(__builtin_amdgcn_exp2f(dv * A2[n+3]), h[n+3], dvx * Bv[n+3]);
            y3 = fmaf(h[n+3], Cv[n+3], y3);
        }
        out[gbase + (size_t)tt * DIN] = ((y0 + y1) + (y2 + y3)) + xv * Dv;
        dv = dv_n; xv = xv_n;
        bq[0] = bqn[0]; bq[1] = bqn[1]; bq[2] = bqn[2]; bq[3] = bqn[3];
        cq[0] = cqn[0]; cq[1] = cqn[1]; cq[2] = cqn[2]; cq[3] = cqn[3];
    }
}

extern "C" void kernel_launch(void* const* d_in, const int* in_sizes, int n_in,
                              void* d_out, int out_size, void* d_ws, size_t ws_size,
                              hipStream_t stream) {
    const float* x     = (const float*)d_in[0];
    const float* A_log = (const float*)d_in[1];
    const float* Dw    = (const float*)d_in[2];
    const float* xpw   = (const float*)d_in[3];
    const float* dtw   = (const float*)d_in[4];
    const float* dtb   = (const float*)d_in[5];
    float* out = (float*)d_out;

    char* ws = (char*)d_ws;
    size_t off = 0;
    float* xdbl  = (float*)(ws + off); off += (size_t)MROWS * EOUT * 4;           // 3.15 MB
    float* hend0 = (float*)(ws + off); off += (size_t)BATCH * NC * DIN * NST * 4; // 20.97 MB
    float* hinit = (float*)(ws + off); off += (size_t)BATCH * NC * DIN * NST * 4; // 20.97 MB
    float* Sbuf  = (float*)(ws + off); off += (size_t)BATCH * NC * DIN * 4;       // 1.31 MB
    ushort* aHi  = (ushort*)(ws + off); off += (size_t)MROWS * RDT * 2;           // 1.31 MB
    ushort* aLo  = (ushort*)(ws + off); off += (size_t)MROWS * RDT * 2;           // 1.31 MB
    ushort* bW   = (ushort*)(ws + off); off += (size_t)DIN * RDT * 2;             // 1.64 MB
    ushort* bWp  = (ushort*)(ws + off); off += (size_t)EOUT * DIN * 2;            // 1.97 MB
    const size_t delta_off = off;
    const bool f32ok = ws_size >= delta_off + (size_t)MROWS * DIN * 4;

    k0_cvtw<<<dim3(EOUT * DIN / 4 / 256), 256, 0, stream>>>(xpw, bWp);
    k0_cvtw<<<dim3(DIN * RDT / 4 / 256), 256, 0, stream>>>(dtw, bW);

    if (f32ok) {
        // split-K=16 partials (50.3 MB) alias the fp32 delta region (84 MB, dead until k2)
        float* part = (float*)(ws + delta_off);
        float* delta = (float*)(ws + delta_off);
        k1_mfma<DIN / 16><<<dim3(MROWS / 128, 16), 256, 0, stream>>>(x, bWp, part);
        k1_reduce<16><<<dim3(MROWS * EOUT / 4 / 256), 256, 0, stream>>>(part, xdbl, aHi, aLo);
        k2_mfma<float><<<dim3(MROWS / 64, DIN / 256), 256, 0, stream>>>(aHi, aLo, bW, dtb, delta);
        k3a_local<float><<<dim3(DIN / 256, NC, BATCH), 256, 0, stream>>>(x, delta, xdbl, A_log, Sbuf, hend0);
        k3b_combine<<<dim3(BATCH * DIN * NST / 256), 256, 0, stream>>>(Sbuf, hend0, A_log, hinit);
        k3c_scan<float><<<dim3(DIN / 256, NC, BATCH), 256, 0, stream>>>(x, delta, xdbl, A_log, Dw, hinit, out);
    } else {
        // split-K=8 partials (25.2 MB) alias hend0+hinit (dead until k3a)
        float* part = hend0;
        __hip_bfloat16* delta = (__hip_bfloat16*)(ws + delta_off);
        k1_mfma<DIN / 8><<<dim3(MROWS / 128, 8), 256, 0, stream>>>(x, bWp, part);
        k1_reduce<8><<<dim3(MROWS * EOUT / 4 / 256), 256, 0, stream>>>(part, xdbl, aHi, aLo);
        k2_mfma<__hip_bfloat16><<<dim3(MROWS / 64, DIN / 256), 256, 0, stream>>>(aHi, aLo, bW, dtb, delta);
        k3a_local<__hip_bfloat16><<<dim3(DIN / 256, NC, BATCH), 256, 0, stream>>>(x, delta, xdbl, A_log, Sbuf, hend0);
        k3b_combine<<<dim3(BATCH * DIN * NST / 256), 256, 0, stream>>>(Sbuf, hend0, A_log, hinit);
        k3c_scan<__hip_bfloat16><<<dim3(DIN / 256, NC, BATCH), 256, 0, stream>>>(x, delta, xdbl, A_log, Dw, hinit, out);
    }
}